// Round 17
// baseline (292.602 us; speedup 1.0000x reference)
//
#include <hip/hip_runtime.h>
#include <hip/hip_bf16.h>
#include <math.h>

// Problem constants (B=32, T=256, V=32000, D=512)
#define R   8192    // B*T rows
#define TT  256
#define D   512
#define V   32000
#define G3  1536    // 3*D (z|f|o)

typedef __attribute__((ext_vector_type(4))) float f32x4;
typedef __attribute__((ext_vector_type(4))) int   i32x4;
typedef __attribute__((ext_vector_type(8))) int   i32x8;

__device__ __forceinline__ float bf2f(ushort u) {
  union { unsigned int i; float f; } x; x.i = ((unsigned int)u) << 16; return x.f;
}
__device__ __forceinline__ ushort f2bf(float f) {   // RNE
  union { float f; unsigned int i; } x; x.f = f;
  unsigned int r = x.i + 0x7fffu + ((x.i >> 16) & 1u);
  return (ushort)(r >> 16);
}

// f32 -> OCP e4m3fn, RNE, clamp 448.
__device__ __forceinline__ unsigned char f2e4m3(float f) {
  unsigned char s = (__float_as_uint(f) >> 31) ? 0x80 : 0x00;
  float a = fabsf(f);
  if (!(a < 448.f)) return s | 0x7e;
  if (a == 0.f) return s;
  int ef; frexpf(a, &ef);
  int E = ef - 1;
  if (E < -6) E = -6;
  float ulp = ldexpf(1.f, E - 3);
  int qi = (int)rintf(a / ulp);
  if (qi >= 16) { E += 1; qi = 8; }
  unsigned char bits = (qi < 8) ? (unsigned char)qi
                                : (unsigned char)(((E + 7) << 3) | (qi - 8));
  return s | bits;
}

// OCP e4m3fn -> f32
__device__ __forceinline__ float e4m3f(unsigned char b) {
  int e = (b >> 3) & 15, m = b & 7;
  float v;
  if (e == 0) v = (float)m * 0.001953125f;
  else { union { unsigned u; float f; } x;
         x.u = ((unsigned)(e + 120) << 23) | ((unsigned)m << 20); v = x.f; }
  return (b & 0x80) ? -v : v;
}

// f32 (pre-scaled) -> fp4 e2m1 code, RNE to grid {0,.5,1,1.5,2,3,4,6}, clamp 6.
__device__ __forceinline__ unsigned char f2e2m1(float v) {
  unsigned char s = (v < 0.f) ? 8 : 0;
  float a = fabsf(v);
  unsigned char q;
  if      (a < 0.25f) q = 0;
  else if (a < 0.75f) q = 1;
  else if (a < 1.25f) q = 2;
  else if (a < 1.75f) q = 3;
  else if (a < 2.5f)  q = 4;
  else if (a < 3.5f)  q = 5;
  else if (a < 5.0f)  q = 6;
  else                q = 7;
  return s | q;
}

// phys-K transpose within each 128-elem block (nibble units for fp4, byte for fp8):
// elem k -> (k&~127) | h*32 | ks*8 | j,  k = (k&~127)+ks*32+h*8+j.
__device__ __forceinline__ int physk(int d) {
  return (d & ~127) | (((d >> 3) & 3) << 5) | (((d >> 5) & 3) << 3) | (d & 7);
}
// within-128-block nibble offset
__device__ __forceinline__ int physwb(int k) {
  return (((k >> 3) & 3) << 5) | (((k >> 5) & 3) << 3) | (k & 7);
}

__device__ __forceinline__ void gload16(const void* g, void* l) {
  __builtin_amdgcn_global_load_lds((const __attribute__((address_space(1))) void*)g,
                                   (__attribute__((address_space(3))) void*)l, 16, 0, 0);
}

// ---------------- embedding gather -> XA4 fp4 phys-K [R][1024 elems]=[512B], x*16 ----------------
__global__ __launch_bounds__(256) void embed_kernel(const int* __restrict__ tok,
                                                    const float4* __restrict__ emb,
                                                    unsigned char* __restrict__ XA4) {
  int idx = blockIdx.x * 256 + threadIdx.x;   // over R*128 float4s
  int r = idx >> 7, d4 = idx & 127;
  float4 v = emb[(size_t)tok[r] * 128 + d4];
  int d = d4 * 4;
  unsigned char n0 = f2e2m1(v.x * 16.f), n1 = f2e2m1(v.y * 16.f);
  unsigned char n2 = f2e2m1(v.z * 16.f), n3 = f2e2m1(v.w * 16.f);
  uchar2 b2; b2.x = n0 | (n1 << 4); b2.y = n2 | (n3 << 4);
  int bx2 = (((d & ~127) + physwb(d & 127)) >> 1);   // byte offset of elem-pair run
  *(uchar2*)(XA4 + (size_t)r * 512 + 256 + bx2) = b2;            // x part
  int t = r & (TT - 1);
  if (t < TT - 1) *(uchar2*)(XA4 + (size_t)(r + 1) * 512 + bx2) = b2;  // next row x_prev
  if (t == 0) { uchar2 z = {0, 0}; *(uchar2*)(XA4 + (size_t)r * 512 + bx2) = z; }
}

// ---------------- fp8 phys-K transpose-convert (for SW8T / tgl path) ----------------
__device__ __forceinline__ void tconv_write(const float (*tile)[65],
                                            unsigned char* __restrict__ dstrow0,
                                            size_t ldb, int k0, int t) {
  int nn = t & 63, h = t >> 6;
  union { unsigned char c[16]; uint4 q; } u;
#pragma unroll
  for (int ksl = 0; ksl < 2; ++ksl)
#pragma unroll
    for (int j = 0; j < 8; ++j)
      u.c[ksl * 8 + j] = f2e4m3(tile[ksl * 32 + h * 8 + j][nn]);
  unsigned char* dst = dstrow0 + (size_t)nn * ldb + (k0 & ~127) + h * 32 + ((k0 & 64) ? 16 : 0);
  *(uint4*)dst = u.q;
}

// fp4 variant: same phys map in NIBBLE units; 16 elems -> 8 bytes (low nibble = even j).
__device__ __forceinline__ void tconv4_write(const float (*tile)[65],
                                             unsigned char* __restrict__ dstrow0,
                                             size_t ldb4, int k0, int t, float scale) {
  int nn = t & 63, h = t >> 6;
  union { unsigned char c[8]; uint2 q; } u;
#pragma unroll
  for (int ksl = 0; ksl < 2; ++ksl)
#pragma unroll
    for (int jp = 0; jp < 4; ++jp) {
      unsigned char l4 = f2e2m1(tile[ksl * 32 + h * 8 + jp * 2    ][nn] * scale);
      unsigned char h4 = f2e2m1(tile[ksl * 32 + h * 8 + jp * 2 + 1][nn] * scale);
      u.c[ksl * 4 + jp] = l4 | (h4 << 4);
    }
  unsigned char* dst = dstrow0 + (size_t)nn * ldb4 + ((k0 & ~127) >> 1) + h * 16 + ((k0 & 64) ? 8 : 0);
  *(uint2*)dst = u.q;
}

// ---------------- weight transpose+convert (BOTH layers): WT4[1536][512B] fp4 phys-K, W*16 ----------------
__global__ __launch_bounds__(256) void wconv(const float* __restrict__ Wz0,
                                             const float* __restrict__ Wf0,
                                             const float* __restrict__ Wo0,
                                             const float* __restrict__ Wz1,
                                             const float* __restrict__ Wf1,
                                             const float* __restrict__ Wo1,
                                             unsigned char* __restrict__ WT40,
                                             unsigned char* __restrict__ WT41) {
  __shared__ float tile[64][65];
  int z = blockIdx.z;
  int layer = z >= 6 ? 1 : 0, zz = z - 6 * layer;
  int g = zz >> 1, i = zz & 1;
  const float* src = layer == 0 ? (g == 0 ? Wz0 : (g == 1 ? Wf0 : Wo0))
                                : (g == 0 ? Wz1 : (g == 1 ? Wf1 : Wo1));
  unsigned char* WT4 = layer == 0 ? WT40 : WT41;
  src += (size_t)i * D * D;
  int d0 = blockIdx.x * 64, e0 = blockIdx.y * 64;
  int t = threadIdx.x, c = t & 63, rq = t >> 6;
#pragma unroll
  for (int p = 0; p < 16; ++p) {
    int dd = p * 4 + rq;
    tile[dd][c] = src[(size_t)(d0 + dd) * D + e0 + c];   // [k=d][n=e]
  }
  __syncthreads();
  tconv4_write(tile, WT4 + (size_t)(g * D + e0) * 512, 512, i * 512 + d0, t, 16.f);
}

// ---------------- softmax weight transpose+convert: fp8 (tgl) + fp4 x32 (lse) ----------------
__global__ __launch_bounds__(256) void swconv(const float* __restrict__ SW,
                                              unsigned char* __restrict__ SWT,
                                              unsigned char* __restrict__ SW4T) {
  __shared__ float tile[64][65];
  int k0 = blockIdx.x * 64, n0 = blockIdx.y * 64;
  int t = threadIdx.x, c = t & 63, rq = t >> 6;
#pragma unroll
  for (int p = 0; p < 16; ++p) {
    int kk = p * 4 + rq;
    tile[kk][c] = SW[(size_t)(k0 + kk) * V + n0 + c];
  }
  __syncthreads();
  tconv_write(tile, SWT + (size_t)n0 * 512, 512, k0, t);
  tconv4_write(tile, SW4T + (size_t)n0 * 256, 256, k0, t, 32.f);   // W x 2^5
}

// ---------------- H8 (fp8 phys-K) -> H4 (fp4 phys-K, x4 scale) repack ----------------
__global__ __launch_bounds__(256) void h4pack(const unsigned char* __restrict__ H8,
                                              unsigned char* __restrict__ H4) {
  int i = blockIdx.x * 256 + threadIdx.x;       // over R*512/8 chunks
  uint2 v = *(const uint2*)(H8 + (size_t)i * 8);
  union { unsigned char c[4]; unsigned int q; } u;
#pragma unroll
  for (int b = 0; b < 4; ++b) {
    unsigned int w = (b < 2) ? v.x : v.y;
    int sh = (b & 1) * 16;
    unsigned char e0 = (w >> sh) & 255, e1 = (w >> (sh + 8)) & 255;
    u.c[b] = f2e2m1(e4m3f(e0) * 4.f) | (f2e2m1(e4m3f(e1) * 4.f) << 4);
  }
  *(unsigned int*)(H4 + (size_t)i * 4) = u.q;
}

// ---------------- shared MX-fp4 256x128 GEMM core (VERIFIED r16 structure) ----------------
// 256 thr / 4 waves; wave tile 128x64. Row-per-kt = 64B = 4 slots of 16B;
// phys slot = (logical + swz(r)) & 3, swz(r) = ((r&3)+((r>>2)&3))&3 (<=2-way, free).
// Swapped MFMA (mfma(W, A)): C row = lane&15 (lane-local), C col = (lane>>4)*4+j.
// WSC/ASC: e8m0 scale bytes applied to W (first operand) / A (second operand).
template<int LD4, int NKT, int WSC, int ASC>
__device__ __forceinline__ void mx4_core(const unsigned char* __restrict__ A4,
                                         const unsigned char* __restrict__ B4,
                                         int row0, int col0, char* lds,
                                         f32x4 acc[8][4]) {
  char* As = lds;            // 256 rows x 64B
  char* Bs = lds + 16384;    // 128 rows x 64B
  const int t = threadIdx.x, lane = t & 63, w = t >> 6;
  const int wm = w >> 1, wn = w & 1;
  const int lo = lane & 15, hi = lane >> 4;
  const int gr = t >> 2;                                       // row within issue
  const int ls = ((t & 3) - ((gr & 3) + ((gr >> 2) & 3))) & 3; // inverse-swz source slot

#pragma unroll 1
  for (int kt = 0; kt < NKT; ++kt) {
    const int k0b = kt * 64;                 // byte offset within row
#pragma unroll
    for (int i = 0; i < 4; ++i)
      gload16(A4 + (size_t)(row0 + i * 64 + gr) * LD4 + k0b + ls * 16,
              As + i * 4096 + t * 16);
#pragma unroll
    for (int i = 0; i < 2; ++i)
      gload16(B4 + (size_t)(col0 + i * 64 + gr) * LD4 + k0b + ls * 16,
              Bs + i * 4096 + t * 16);
    __syncthreads();
    i32x8 b4[4];
#pragma unroll
    for (int ni = 0; ni < 4; ++ni) {
      int r = wn * 64 + ni * 16 + lo;
      int ps = (hi + (r & 3) + ((r >> 2) & 3)) & 3;
      union { i32x8 v8; i32x4 v4[2]; } u;
      u.v4[0] = *(const i32x4*)(Bs + r * 64 + ps * 16);
      i32x4 z4 = {0, 0, 0, 0};
      u.v4[1] = z4;
      b4[ni] = u.v8;
    }
#pragma unroll
    for (int mi = 0; mi < 8; ++mi) {
      int r = wm * 128 + mi * 16 + lo;
      int ps = (hi + (r & 3) + ((r >> 2) & 3)) & 3;
      union { i32x8 v8; i32x4 v4[2]; } u;
      u.v4[0] = *(const i32x4*)(As + r * 64 + ps * 16);
      i32x4 z4 = {0, 0, 0, 0};
      u.v4[1] = z4;
      i32x8 a4 = u.v8;
#pragma unroll
      for (int ni = 0; ni < 4; ++ni)
        acc[mi][ni] = __builtin_amdgcn_mfma_scale_f32_16x16x128_f8f6f4(
            b4[ni], a4, acc[mi][ni], 4, 4, 0, WSC, 0, ASC);
    }
    __syncthreads();
  }
}

// ---------------- QRNN pre-activation GEMM (8192x1536x1024, MX-fp4, fused bias) ----------------
// ASC: layer1 A=x*16 -> 123; layer2 A=h*4 -> 125. W*16 -> 123.
template<int ASC>
__global__ __launch_bounds__(256, 2) void gemm_pre_fp4(const unsigned char* __restrict__ A4,
                                                       const unsigned char* __restrict__ B4,
                                                       const float* __restrict__ bz,
                                                       const float* __restrict__ bf,
                                                       const float* __restrict__ bo,
                                                       ushort* __restrict__ PRE) {
  __shared__ char lds[24576];
  const int t = threadIdx.x, lane = t & 63, w = t >> 6;
  const int wm = w >> 1, wn = w & 1;
  const int lo = lane & 15, hi = lane >> 4;
  const int row0 = blockIdx.x * 256, col0 = blockIdx.y * 128;
  const int g = col0 >> 9;                       // gate uniform per block
  const float* bg = (g == 0) ? bz : (g == 1 ? bf : bo);

  f32x4 acc[8][4];
#pragma unroll
  for (int i = 0; i < 8; ++i)
#pragma unroll
    for (int j = 0; j < 4; ++j) { f32x4 z = {0.f,0.f,0.f,0.f}; acc[i][j] = z; }

  mx4_core<512, 8, 123, ASC>(A4, B4, row0, col0, lds, acc);

#pragma unroll
  for (int mi = 0; mi < 8; ++mi) {
    const int row = row0 + wm * 128 + mi * 16 + lo;
#pragma unroll
    for (int ni = 0; ni < 4; ++ni) {
      const int colb = col0 + wn * 64 + ni * 16 + hi * 4;
      const int eb = colb & 511;
      ushort4 v;
      v.x = f2bf(acc[mi][ni][0] + bg[eb + 0]);
      v.y = f2bf(acc[mi][ni][1] + bg[eb + 1]);
      v.z = f2bf(acc[mi][ni][2] + bg[eb + 2]);
      v.w = f2bf(acc[mi][ni][3] + bg[eb + 3]);
      *(ushort4*)(PRE + (size_t)row * G3 + colb) = v;
    }
  }
}

// ---------------- target-logit kernel (+ SUM zero): fp8 path (unchanged, accurate) ----------------
__global__ __launch_bounds__(256) void tgl_kernel(const unsigned char* __restrict__ H8,
                                                  const unsigned char* __restrict__ SWT,
                                                  const float* __restrict__ SB,
                                                  const int* __restrict__ tgt,
                                                  float* __restrict__ TGL,
                                                  float* __restrict__ SUM) {
  int wid  = (blockIdx.x * 256 + threadIdx.x) >> 6;   // one wave per row
  int lane = threadIdx.x & 63;
  if (lane == 0) SUM[wid] = 0.f;                      // zero before lse's atomics
  int tg = tgt[wid];
  uint2 hv = *(const uint2*)(H8  + (size_t)wid * 512 + lane * 8);
  uint2 wv = *(const uint2*)(SWT + (size_t)tg  * 512 + lane * 8);
  float s = 0.f;
#pragma unroll
  for (int k = 0; k < 4; ++k)
    s += e4m3f((hv.x >> (8 * k)) & 255) * e4m3f((wv.x >> (8 * k)) & 255);
#pragma unroll
  for (int k = 0; k < 4; ++k)
    s += e4m3f((hv.y >> (8 * k)) & 255) * e4m3f((wv.y >> (8 * k)) & 255);
#pragma unroll
  for (int m = 1; m < 64; m <<= 1) s += __shfl_xor(s, m, 64);
  if (lane == 0) TGL[wid] = s + SB[tg];
}

// ---------------- MX-fp4 logits GEMM + fused exp-sum (exp2-folded epilogue) ----------------
__global__ __launch_bounds__(256, 2) void gemm_lse_fp4(const unsigned char* __restrict__ A4,
                                                       const unsigned char* __restrict__ B4,
                                                       const float* __restrict__ SB,
                                                       float* __restrict__ SUM) {
  __shared__ char lds[24576];
  const int t = threadIdx.x, lane = t & 63, w = t >> 6;
  const int wm = w >> 1, wn = w & 1;
  const int lo = lane & 15, hi = lane >> 4;
  const int row0 = blockIdx.x * 256, col0 = blockIdx.y * 128;
  const float L2E = 1.442695041f;

  float sb[16];   // SB * log2(e), pre-folded for exp2
#pragma unroll
  for (int ni = 0; ni < 4; ++ni)
#pragma unroll
    for (int j = 0; j < 4; ++j)
      sb[ni * 4 + j] = SB[col0 + wn * 64 + ni * 16 + hi * 4 + j] * L2E;

  f32x4 acc[8][4];
#pragma unroll
  for (int i = 0; i < 8; ++i)
#pragma unroll
    for (int j = 0; j < 4; ++j) { f32x4 z = {0.f,0.f,0.f,0.f}; acc[i][j] = z; }

  mx4_core<256, 4, 122, 125>(A4, B4, row0, col0, lds, acc);  // W x2^-5, H x2^-2

  // epilogue: exp(x+b) = exp2(x*L2E + b*L2E) -> 1 fma + 1 exp2 per logit
#pragma unroll
  for (int mi = 0; mi < 8; ++mi) {
    const int row = row0 + wm * 128 + mi * 16 + lo;
    float s0 = 0.f, s1 = 0.f, s2 = 0.f, s3 = 0.f;
#pragma unroll
    for (int ni = 0; ni < 4; ++ni) {
      s0 += exp2f(fmaf(acc[mi][ni][0], L2E, sb[ni * 4 + 0]));
      s1 += exp2f(fmaf(acc[mi][ni][1], L2E, sb[ni * 4 + 1]));
      s2 += exp2f(fmaf(acc[mi][ni][2], L2E, sb[ni * 4 + 2]));
      s3 += exp2f(fmaf(acc[mi][ni][3], L2E, sb[ni * 4 + 3]));
    }
    float s = (s0 + s1) + (s2 + s3);
    s += __shfl_xor(s, 16, 64);
    s += __shfl_xor(s, 32, 64);
    if (hi == 0) atomicAdd(&SUM[row], s);
  }
}

// ---------------- fused 4-segment parallel fo-pool scan ----------------
// mode 0: OUT4 = YA4 fp4 phys-K [R][512B], h*4 (lane-pair nibble merge via shfl).
// mode 1: OUT8 = H8 fp8 phys-K [R][512B].
__global__ __launch_bounds__(256) void scan_fused(const ushort* __restrict__ PRE,
                                                  unsigned char* __restrict__ OUT4,
                                                  unsigned char* __restrict__ OUT8,
                                                  int mode) {
  __shared__ float Als[4][64], Bls[4][64];
  const int b = blockIdx.x, dc = blockIdx.y;
  const int tid = threadIdx.x, dl = tid & 63, s = tid >> 6;   // s wave-uniform
  const int d = dc * 64 + dl;
  const ushort* p  = PRE + (size_t)b * TT * G3 + d;
  const ushort* ps = p + (size_t)(s * 64) * G3;

  float a = 1.f, c = 0.f;
  for (int t0 = 0; t0 < 64; t0 += 8) {
    float pz[8], pf[8];
#pragma unroll
    for (int i = 0; i < 8; ++i) {
      const ushort* q = ps + (size_t)(t0 + i) * G3;
      pz[i] = bf2f(q[0]); pf[i] = bf2f(q[512]);
    }
#pragma unroll
    for (int i = 0; i < 8; ++i) {
      float z = 2.f / (1.f + __expf(-2.f * pz[i])) - 1.f;
      float f = 1.f / (1.f + __expf(-pf[i]));
      c = f * c + (1.f - f) * z;
      a *= f;
    }
  }
  Als[s][dl] = a; Bls[s][dl] = c;
  __syncthreads();
  float cc = 0.f;
  for (int u = 0; u < s; ++u)          // wave-uniform bound, no divergence
    cc = Als[u][dl] * cc + Bls[u][dl];

  const int poff = physk(d);                                   // fp8 byte offset
  const int bx2  = (((d & ~127) + physwb(d & 127)) >> 1);      // fp4 pair-byte offset
  for (int t0 = s * 64; t0 < s * 64 + 64; t0 += 8) {
    float pz[8], pf[8], po[8];
#pragma unroll
    for (int i = 0; i < 8; ++i) {
      const ushort* q = p + (size_t)(t0 + i) * G3;
      pz[i] = bf2f(q[0]); pf[i] = bf2f(q[512]); po[i] = bf2f(q[1024]);
    }
#pragma unroll
    for (int i = 0; i < 8; ++i) {
      float z = 2.f / (1.f + __expf(-2.f * pz[i])) - 1.f;
      float f = 1.f / (1.f + __expf(-pf[i]));
      float o = 1.f / (1.f + __expf(-po[i]));
      cc = f * cc + (1.f - f) * z;
      float h = o * cc;
      int tt = t0 + i;
      size_t r = (size_t)b * TT + tt;
      unsigned char nib = f2e2m1(h * 4.f);
      unsigned int pn = __shfl_xor((unsigned int)nib, 1, 64);  // partner (d^1) nibble
      if (mode == 0) {
        if ((dl & 1) == 0) {
          unsigned char byte = nib | ((unsigned char)pn << 4);
          OUT4[r * 512 + 256 + bx2] = byte;                    // x part
          if (tt < TT - 1) OUT4[(r + 1) * 512 + bx2] = byte;   // x_prev of next row
          if (tt == 0)     OUT4[r * 512 + bx2] = 0;
        }
      } else {
        OUT8[r * 512 + poff] = f2e4m3(h);
      }
    }
  }
}

// ---------------- final cost ----------------
__global__ __launch_bounds__(256) void cost_kernel(const float* __restrict__ sumexp,
                                                   const float* __restrict__ tgl,
                                                   float* __restrict__ out) {
  int t = threadIdx.x;
  float s = 0.f;
  for (int r = t; r < R; r += 256) s += logf(sumexp[r]) - tgl[r];
#pragma unroll
  for (int m = 1; m < 64; m <<= 1) s += __shfl_xor(s, m, 64);
  __shared__ float red[4];
  int wave = t >> 6, lane = t & 63;
  if (lane == 0) red[wave] = s;
  __syncthreads();
  if (t == 0) out[0] = (red[0] + red[1] + red[2] + red[3]) / (float)R;
}

extern "C" void kernel_launch(void* const* d_in, const int* in_sizes, int n_in,
                              void* d_out, int out_size, void* d_ws, size_t ws_size,
                              hipStream_t stream) {
  const int*   tok = (const int*)d_in[0];
  const int*   tgt = (const int*)d_in[1];
  const float* emb = (const float*)d_in[2];
  const float* Wz0 = (const float*)d_in[3];  const float* bz0 = (const float*)d_in[4];
  const float* Wf0 = (const float*)d_in[5];  const float* bf0 = (const float*)d_in[6];
  const float* Wo0 = (const float*)d_in[7];  const float* bo0 = (const float*)d_in[8];
  const float* Wz1 = (const float*)d_in[9];  const float* bz1 = (const float*)d_in[10];
  const float* Wf1 = (const float*)d_in[11]; const float* bf1 = (const float*)d_in[12];
  const float* Wo1 = (const float*)d_in[13]; const float* bo1 = (const float*)d_in[14];
  const float* SW  = (const float*)d_in[15]; const float* SB  = (const float*)d_in[16];
  float* out = (float*)d_out;

  // workspace layout (bytes), max ~49.7 MB:
  char* base = (char*)d_ws;
  unsigned char* XA4  = (unsigned char*)(base);             //  4,194,304 [R][512B] fp4
  unsigned char* YA4  = (unsigned char*)(base + 4194304);   //  4,194,304
  ushort*        PRE  = (ushort*)(base + 8388608);          // 25,165,824 [R][1536] bf16
  unsigned char* H8   = (unsigned char*)(base + 33554432);  //  4,194,304 [R][512B] fp8
  unsigned char* WT40 = (unsigned char*)(base + 37748736);  //    786,432 [1536][512B] fp4
  unsigned char* WT41 = (unsigned char*)(base + 38535168);  //    786,432
  float*         SUM  = (float*)(base + 39321600);          //     32,768
  float*         TGL  = (float*)(base + 39354368);          //     32,768
  unsigned char* H4   = (unsigned char*)(base + 39387136);  //  2,097,152 [R][256B] fp4
  unsigned char* SW4T = (unsigned char*)(base + 41484288);  //  8,192,000 [V][256B] fp4
  unsigned char* SW8T = (unsigned char*)(base);             // 16,384,000 — aliases XA4+YA4+PRE[0:8M] (dead by then)

  embed_kernel<<<R * 128 / 256, 256, 0, stream>>>(tok, (const float4*)emb, XA4);
  wconv<<<dim3(8, 8, 12), 256, 0, stream>>>(Wz0, Wf0, Wo0, Wz1, Wf1, Wo1, WT40, WT41);

  gemm_pre_fp4<123><<<dim3(32, 12), 256, 0, stream>>>(XA4, WT40, bz0, bf0, bo0, PRE);  // A=x*16
  scan_fused<<<dim3(32, 8), 256, 0, stream>>>(PRE, YA4, nullptr, 0);
  gemm_pre_fp4<125><<<dim3(32, 12), 256, 0, stream>>>(YA4, WT41, bz1, bf1, bo1, PRE);  // A=h*4
  scan_fused<<<dim3(32, 8), 256, 0, stream>>>(PRE, nullptr, H8, 1);

  // SW8T aliases XA4/YA4/PRE-head — all dead after the second scan
  swconv<<<dim3(8, 500), 256, 0, stream>>>(SW, SW8T, SW4T);
  h4pack<<<R * 512 / 8 / 256, 256, 0, stream>>>(H8, H4);
  tgl_kernel<<<R / 4, 256, 0, stream>>>(H8, SW8T, SB, tgt, TGL, SUM);
  gemm_lse_fp4<<<dim3(32, 250), 256, 0, stream>>>(H4, SW4T, SB, SUM);
  cost_kernel<<<1, 256, 0, stream>>>(SUM, TGL, out);
}

// Round 18
// 266.552 us; speedup vs baseline: 1.0977x; 1.0977x over previous
//
#include <hip/hip_runtime.h>
#include <hip/hip_bf16.h>
#include <math.h>

// Problem constants (B=32, T=256, V=32000, D=512)
#define R   8192    // B*T rows
#define TT  256
#define D   512
#define V   32000
#define G3  1536    // 3*D (z|f|o)

typedef __attribute__((ext_vector_type(4))) float f32x4;
typedef __attribute__((ext_vector_type(4))) int   i32x4;
typedef __attribute__((ext_vector_type(8))) int   i32x8;

__device__ __forceinline__ float bf2f(ushort u) {
  union { unsigned int i; float f; } x; x.i = ((unsigned int)u) << 16; return x.f;
}
__device__ __forceinline__ ushort f2bf(float f) {   // RNE
  union { float f; unsigned int i; } x; x.f = f;
  unsigned int r = x.i + 0x7fffu + ((x.i >> 16) & 1u);
  return (ushort)(r >> 16);
}

// raw hardware exp2: exactly the terminal op of __expf, no libm guards
__device__ __forceinline__ float hw_exp2(float x) {
  float r;
  asm("v_exp_f32 %0, %1" : "=v"(r) : "v"(x));
  return r;
}

// f32 -> OCP e4m3fn, RNE, clamp 448.
__device__ __forceinline__ unsigned char f2e4m3(float f) {
  unsigned char s = (__float_as_uint(f) >> 31) ? 0x80 : 0x00;
  float a = fabsf(f);
  if (!(a < 448.f)) return s | 0x7e;
  if (a == 0.f) return s;
  int ef; frexpf(a, &ef);
  int E = ef - 1;
  if (E < -6) E = -6;
  float ulp = ldexpf(1.f, E - 3);
  int qi = (int)rintf(a / ulp);
  if (qi >= 16) { E += 1; qi = 8; }
  unsigned char bits = (qi < 8) ? (unsigned char)qi
                                : (unsigned char)(((E + 7) << 3) | (qi - 8));
  return s | bits;
}

// OCP e4m3fn -> f32
__device__ __forceinline__ float e4m3f(unsigned char b) {
  int e = (b >> 3) & 15, m = b & 7;
  float v;
  if (e == 0) v = (float)m * 0.001953125f;
  else { union { unsigned u; float f; } x;
         x.u = ((unsigned)(e + 120) << 23) | ((unsigned)m << 20); v = x.f; }
  return (b & 0x80) ? -v : v;
}

// f32 (pre-scaled) -> fp4 e2m1 code, RNE to grid {0,.5,1,1.5,2,3,4,6}, clamp 6.
__device__ __forceinline__ unsigned char f2e2m1(float v) {
  unsigned char s = (v < 0.f) ? 8 : 0;
  float a = fabsf(v);
  unsigned char q;
  if      (a < 0.25f) q = 0;
  else if (a < 0.75f) q = 1;
  else if (a < 1.25f) q = 2;
  else if (a < 1.75f) q = 3;
  else if (a < 2.5f)  q = 4;
  else if (a < 3.5f)  q = 5;
  else if (a < 5.0f)  q = 6;
  else                q = 7;
  return s | q;
}

// phys-K transpose within each 128-elem block (nibble units for fp4, byte for fp8):
// elem k -> (k&~127) | h*32 | ks*8 | j,  k = (k&~127)+ks*32+h*8+j.
__device__ __forceinline__ int physk(int d) {
  return (d & ~127) | (((d >> 3) & 3) << 5) | (((d >> 5) & 3) << 3) | (d & 7);
}
// within-128-block nibble offset
__device__ __forceinline__ int physwb(int k) {
  return (((k >> 3) & 3) << 5) | (((k >> 5) & 3) << 3) | (k & 7);
}

__device__ __forceinline__ void gload16(const void* g, void* l) {
  __builtin_amdgcn_global_load_lds((const __attribute__((address_space(1))) void*)g,
                                   (__attribute__((address_space(3))) void*)l, 16, 0, 0);
}

// ---------------- embedding gather -> XA4 fp4 phys-K [R][1024 elems]=[512B], x*16 ----------------
__global__ __launch_bounds__(256) void embed_kernel(const int* __restrict__ tok,
                                                    const float4* __restrict__ emb,
                                                    unsigned char* __restrict__ XA4) {
  int idx = blockIdx.x * 256 + threadIdx.x;   // over R*128 float4s
  int r = idx >> 7, d4 = idx & 127;
  float4 v = emb[(size_t)tok[r] * 128 + d4];
  int d = d4 * 4;
  unsigned char n0 = f2e2m1(v.x * 16.f), n1 = f2e2m1(v.y * 16.f);
  unsigned char n2 = f2e2m1(v.z * 16.f), n3 = f2e2m1(v.w * 16.f);
  uchar2 b2; b2.x = n0 | (n1 << 4); b2.y = n2 | (n3 << 4);
  int bx2 = (((d & ~127) + physwb(d & 127)) >> 1);   // byte offset of elem-pair run
  *(uchar2*)(XA4 + (size_t)r * 512 + 256 + bx2) = b2;            // x part
  int t = r & (TT - 1);
  if (t < TT - 1) *(uchar2*)(XA4 + (size_t)(r + 1) * 512 + bx2) = b2;  // next row x_prev
  if (t == 0) { uchar2 z = {0, 0}; *(uchar2*)(XA4 + (size_t)r * 512 + bx2) = z; }
}

// ---------------- fp8 phys-K transpose-convert (for SW8T / tgl path) ----------------
__device__ __forceinline__ void tconv_write(const float (*tile)[65],
                                            unsigned char* __restrict__ dstrow0,
                                            size_t ldb, int k0, int t) {
  int nn = t & 63, h = t >> 6;
  union { unsigned char c[16]; uint4 q; } u;
#pragma unroll
  for (int ksl = 0; ksl < 2; ++ksl)
#pragma unroll
    for (int j = 0; j < 8; ++j)
      u.c[ksl * 8 + j] = f2e4m3(tile[ksl * 32 + h * 8 + j][nn]);
  unsigned char* dst = dstrow0 + (size_t)nn * ldb + (k0 & ~127) + h * 32 + ((k0 & 64) ? 16 : 0);
  *(uint4*)dst = u.q;
}

// fp4 variant: same phys map in NIBBLE units; 16 elems -> 8 bytes (low nibble = even j).
__device__ __forceinline__ void tconv4_write(const float (*tile)[65],
                                             unsigned char* __restrict__ dstrow0,
                                             size_t ldb4, int k0, int t, float scale) {
  int nn = t & 63, h = t >> 6;
  union { unsigned char c[8]; uint2 q; } u;
#pragma unroll
  for (int ksl = 0; ksl < 2; ++ksl)
#pragma unroll
    for (int jp = 0; jp < 4; ++jp) {
      unsigned char l4 = f2e2m1(tile[ksl * 32 + h * 8 + jp * 2    ][nn] * scale);
      unsigned char h4 = f2e2m1(tile[ksl * 32 + h * 8 + jp * 2 + 1][nn] * scale);
      u.c[ksl * 4 + jp] = l4 | (h4 << 4);
    }
  unsigned char* dst = dstrow0 + (size_t)nn * ldb4 + ((k0 & ~127) >> 1) + h * 16 + ((k0 & 64) ? 8 : 0);
  *(uint2*)dst = u.q;
}

// ---------------- weight transpose+convert (BOTH layers): WT4[1536][512B] fp4 phys-K, W*16 ----------------
__global__ __launch_bounds__(256) void wconv(const float* __restrict__ Wz0,
                                             const float* __restrict__ Wf0,
                                             const float* __restrict__ Wo0,
                                             const float* __restrict__ Wz1,
                                             const float* __restrict__ Wf1,
                                             const float* __restrict__ Wo1,
                                             unsigned char* __restrict__ WT40,
                                             unsigned char* __restrict__ WT41) {
  __shared__ float tile[64][65];
  int z = blockIdx.z;
  int layer = z >= 6 ? 1 : 0, zz = z - 6 * layer;
  int g = zz >> 1, i = zz & 1;
  const float* src = layer == 0 ? (g == 0 ? Wz0 : (g == 1 ? Wf0 : Wo0))
                                : (g == 0 ? Wz1 : (g == 1 ? Wf1 : Wo1));
  unsigned char* WT4 = layer == 0 ? WT40 : WT41;
  src += (size_t)i * D * D;
  int d0 = blockIdx.x * 64, e0 = blockIdx.y * 64;
  int t = threadIdx.x, c = t & 63, rq = t >> 6;
#pragma unroll
  for (int p = 0; p < 16; ++p) {
    int dd = p * 4 + rq;
    tile[dd][c] = src[(size_t)(d0 + dd) * D + e0 + c];   // [k=d][n=e]
  }
  __syncthreads();
  tconv4_write(tile, WT4 + (size_t)(g * D + e0) * 512, 512, i * 512 + d0, t, 16.f);
}

// ---------------- softmax weight transpose+convert: fp8 (tgl) + fp4 x32 (lse) ----------------
__global__ __launch_bounds__(256) void swconv(const float* __restrict__ SW,
                                              unsigned char* __restrict__ SWT,
                                              unsigned char* __restrict__ SW4T) {
  __shared__ float tile[64][65];
  int k0 = blockIdx.x * 64, n0 = blockIdx.y * 64;
  int t = threadIdx.x, c = t & 63, rq = t >> 6;
#pragma unroll
  for (int p = 0; p < 16; ++p) {
    int kk = p * 4 + rq;
    tile[kk][c] = SW[(size_t)(k0 + kk) * V + n0 + c];
  }
  __syncthreads();
  tconv_write(tile, SWT + (size_t)n0 * 512, 512, k0, t);
  tconv4_write(tile, SW4T + (size_t)n0 * 256, 256, k0, t, 32.f);   // W x 2^5
}

// ---------------- H8 (fp8 phys-K) -> H4 (fp4 phys-K, x4 scale) repack ----------------
__global__ __launch_bounds__(256) void h4pack(const unsigned char* __restrict__ H8,
                                              unsigned char* __restrict__ H4) {
  int i = blockIdx.x * 256 + threadIdx.x;       // over R*512/8 chunks
  uint2 v = *(const uint2*)(H8 + (size_t)i * 8);
  union { unsigned char c[4]; unsigned int q; } u;
#pragma unroll
  for (int b = 0; b < 4; ++b) {
    unsigned int w = (b < 2) ? v.x : v.y;
    int sh = (b & 1) * 16;
    unsigned char e0 = (w >> sh) & 255, e1 = (w >> (sh + 8)) & 255;
    u.c[b] = f2e2m1(e4m3f(e0) * 4.f) | (f2e2m1(e4m3f(e1) * 4.f) << 4);
  }
  *(unsigned int*)(H4 + (size_t)i * 4) = u.q;
}

// ---------------- shared MX-fp4 256x128 GEMM core (VERIFIED r16/r17) ----------------
// 256 thr / 4 waves; wave tile 128x64. Row-per-kt = 64B = 4 slots of 16B;
// phys slot = (logical + swz(r)) & 3, swz(r) = ((r&3)+((r>>2)&3))&3 (<=2-way, free).
// Swapped MFMA (mfma(W, A)): C row = lane&15 (lane-local), C col = (lane>>4)*4+j.
template<int LD4, int NKT, int WSC, int ASC>
__device__ __forceinline__ void mx4_core(const unsigned char* __restrict__ A4,
                                         const unsigned char* __restrict__ B4,
                                         int row0, int col0, char* lds,
                                         f32x4 acc[8][4]) {
  char* As = lds;            // 256 rows x 64B
  char* Bs = lds + 16384;    // 128 rows x 64B
  const int t = threadIdx.x, lane = t & 63, w = t >> 6;
  const int wm = w >> 1, wn = w & 1;
  const int lo = lane & 15, hi = lane >> 4;
  const int gr = t >> 2;                                       // row within issue
  const int ls = ((t & 3) - ((gr & 3) + ((gr >> 2) & 3))) & 3; // inverse-swz source slot

#pragma unroll 1
  for (int kt = 0; kt < NKT; ++kt) {
    const int k0b = kt * 64;                 // byte offset within row
#pragma unroll
    for (int i = 0; i < 4; ++i)
      gload16(A4 + (size_t)(row0 + i * 64 + gr) * LD4 + k0b + ls * 16,
              As + i * 4096 + t * 16);
#pragma unroll
    for (int i = 0; i < 2; ++i)
      gload16(B4 + (size_t)(col0 + i * 64 + gr) * LD4 + k0b + ls * 16,
              Bs + i * 4096 + t * 16);
    __syncthreads();
    i32x8 b4[4];
#pragma unroll
    for (int ni = 0; ni < 4; ++ni) {
      int r = wn * 64 + ni * 16 + lo;
      int ps = (hi + (r & 3) + ((r >> 2) & 3)) & 3;
      union { i32x8 v8; i32x4 v4[2]; } u;
      u.v4[0] = *(const i32x4*)(Bs + r * 64 + ps * 16);
      i32x4 z4 = {0, 0, 0, 0};
      u.v4[1] = z4;
      b4[ni] = u.v8;
    }
#pragma unroll
    for (int mi = 0; mi < 8; ++mi) {
      int r = wm * 128 + mi * 16 + lo;
      int ps = (hi + (r & 3) + ((r >> 2) & 3)) & 3;
      union { i32x8 v8; i32x4 v4[2]; } u;
      u.v4[0] = *(const i32x4*)(As + r * 64 + ps * 16);
      i32x4 z4 = {0, 0, 0, 0};
      u.v4[1] = z4;
      i32x8 a4 = u.v8;
#pragma unroll
      for (int ni = 0; ni < 4; ++ni)
        acc[mi][ni] = __builtin_amdgcn_mfma_scale_f32_16x16x128_f8f6f4(
            b4[ni], a4, acc[mi][ni], 4, 4, 0, WSC, 0, ASC);
    }
    __syncthreads();
  }
}

// ---------------- QRNN pre-activation GEMM (8192x1536x1024, MX-fp4, fused bias) ----------------
// ASC: layer1 A=x*16 -> 123; layer2 A=h*4 -> 125. W*16 -> 123.
template<int ASC>
__global__ __launch_bounds__(256, 2) void gemm_pre_fp4(const unsigned char* __restrict__ A4,
                                                       const unsigned char* __restrict__ B4,
                                                       const float* __restrict__ bz,
                                                       const float* __restrict__ bf,
                                                       const float* __restrict__ bo,
                                                       ushort* __restrict__ PRE) {
  __shared__ char lds[24576];
  const int t = threadIdx.x, lane = t & 63, w = t >> 6;
  const int wm = w >> 1, wn = w & 1;
  const int lo = lane & 15, hi = lane >> 4;
  const int row0 = blockIdx.x * 256, col0 = blockIdx.y * 128;
  const int g = col0 >> 9;                       // gate uniform per block
  const float* bg = (g == 0) ? bz : (g == 1 ? bf : bo);

  f32x4 acc[8][4];
#pragma unroll
  for (int i = 0; i < 8; ++i)
#pragma unroll
    for (int j = 0; j < 4; ++j) { f32x4 z = {0.f,0.f,0.f,0.f}; acc[i][j] = z; }

  mx4_core<512, 8, 123, ASC>(A4, B4, row0, col0, lds, acc);

#pragma unroll
  for (int mi = 0; mi < 8; ++mi) {
    const int row = row0 + wm * 128 + mi * 16 + lo;
#pragma unroll
    for (int ni = 0; ni < 4; ++ni) {
      const int colb = col0 + wn * 64 + ni * 16 + hi * 4;
      const int eb = colb & 511;
      ushort4 v;
      v.x = f2bf(acc[mi][ni][0] + bg[eb + 0]);
      v.y = f2bf(acc[mi][ni][1] + bg[eb + 1]);
      v.z = f2bf(acc[mi][ni][2] + bg[eb + 2]);
      v.w = f2bf(acc[mi][ni][3] + bg[eb + 3]);
      *(ushort4*)(PRE + (size_t)row * G3 + colb) = v;
    }
  }
}

// ---------------- target-logit kernel (+ SUM zero): fp8 path (unchanged, accurate) ----------------
__global__ __launch_bounds__(256) void tgl_kernel(const unsigned char* __restrict__ H8,
                                                  const unsigned char* __restrict__ SWT,
                                                  const float* __restrict__ SB,
                                                  const int* __restrict__ tgt,
                                                  float* __restrict__ TGL,
                                                  float* __restrict__ SUM) {
  int wid  = (blockIdx.x * 256 + threadIdx.x) >> 6;   // one wave per row
  int lane = threadIdx.x & 63;
  if (lane == 0) SUM[wid] = 0.f;                      // zero before lse's atomics
  int tg = tgt[wid];
  uint2 hv = *(const uint2*)(H8  + (size_t)wid * 512 + lane * 8);
  uint2 wv = *(const uint2*)(SWT + (size_t)tg  * 512 + lane * 8);
  float s = 0.f;
#pragma unroll
  for (int k = 0; k < 4; ++k)
    s += e4m3f((hv.x >> (8 * k)) & 255) * e4m3f((wv.x >> (8 * k)) & 255);
#pragma unroll
  for (int k = 0; k < 4; ++k)
    s += e4m3f((hv.y >> (8 * k)) & 255) * e4m3f((wv.y >> (8 * k)) & 255);
#pragma unroll
  for (int m = 1; m < 64; m <<= 1) s += __shfl_xor(s, m, 64);
  if (lane == 0) TGL[wid] = s + SB[tg];
}

// ---------------- MX-fp4 logits GEMM + fused exp-sum (hw_exp2-folded epilogue) ----------------
__global__ __launch_bounds__(256, 2) void gemm_lse_fp4(const unsigned char* __restrict__ A4,
                                                       const unsigned char* __restrict__ B4,
                                                       const float* __restrict__ SB,
                                                       float* __restrict__ SUM) {
  __shared__ char lds[24576];
  const int t = threadIdx.x, lane = t & 63, w = t >> 6;
  const int wm = w >> 1, wn = w & 1;
  const int lo = lane & 15, hi = lane >> 4;
  const int row0 = blockIdx.x * 256, col0 = blockIdx.y * 128;
  const float L2E = 1.442695041f;

  float sb[16];   // SB * log2(e), pre-folded for the raw v_exp_f32
#pragma unroll
  for (int ni = 0; ni < 4; ++ni)
#pragma unroll
    for (int j = 0; j < 4; ++j)
      sb[ni * 4 + j] = SB[col0 + wn * 64 + ni * 16 + hi * 4 + j] * L2E;

  f32x4 acc[8][4];
#pragma unroll
  for (int i = 0; i < 8; ++i)
#pragma unroll
    for (int j = 0; j < 4; ++j) { f32x4 z = {0.f,0.f,0.f,0.f}; acc[i][j] = z; }

  mx4_core<256, 4, 122, 125>(A4, B4, row0, col0, lds, acc);  // W x2^-5, H x2^-2

  // epilogue: exp(x+b) = v_exp_f32(x*L2E + b*L2E) -> 1 fma + 1 raw exp per logit.
  // (r17 lesson: libm exp2f adds guard code; hw_exp2 is the bare instruction,
  //  identical to __expf's terminal op.)
#pragma unroll
  for (int mi = 0; mi < 8; ++mi) {
    const int row = row0 + wm * 128 + mi * 16 + lo;
    float s0 = 0.f, s1 = 0.f, s2 = 0.f, s3 = 0.f;
#pragma unroll
    for (int ni = 0; ni < 4; ++ni) {
      s0 += hw_exp2(fmaf(acc[mi][ni][0], L2E, sb[ni * 4 + 0]));
      s1 += hw_exp2(fmaf(acc[mi][ni][1], L2E, sb[ni * 4 + 1]));
      s2 += hw_exp2(fmaf(acc[mi][ni][2], L2E, sb[ni * 4 + 2]));
      s3 += hw_exp2(fmaf(acc[mi][ni][3], L2E, sb[ni * 4 + 3]));
    }
    float s = (s0 + s1) + (s2 + s3);
    s += __shfl_xor(s, 16, 64);
    s += __shfl_xor(s, 32, 64);
    if (hi == 0) atomicAdd(&SUM[row], s);
  }
}

// ---------------- fused 4-segment parallel fo-pool scan (r17 exact) ----------------
__global__ __launch_bounds__(256) void scan_fused(const ushort* __restrict__ PRE,
                                                  unsigned char* __restrict__ OUT4,
                                                  unsigned char* __restrict__ OUT8,
                                                  int mode) {
  __shared__ float Als[4][64], Bls[4][64];
  const int b = blockIdx.x, dc = blockIdx.y;
  const int tid = threadIdx.x, dl = tid & 63, s = tid >> 6;   // s wave-uniform
  const int d = dc * 64 + dl;
  const ushort* p  = PRE + (size_t)b * TT * G3 + d;
  const ushort* ps = p + (size_t)(s * 64) * G3;

  float a = 1.f, c = 0.f;
  for (int t0 = 0; t0 < 64; t0 += 8) {
    float pz[8], pf[8];
#pragma unroll
    for (int i = 0; i < 8; ++i) {
      const ushort* q = ps + (size_t)(t0 + i) * G3;
      pz[i] = bf2f(q[0]); pf[i] = bf2f(q[512]);
    }
#pragma unroll
    for (int i = 0; i < 8; ++i) {
      float z = 2.f / (1.f + __expf(-2.f * pz[i])) - 1.f;
      float f = 1.f / (1.f + __expf(-pf[i]));
      c = f * c + (1.f - f) * z;
      a *= f;
    }
  }
  Als[s][dl] = a; Bls[s][dl] = c;
  __syncthreads();
  float cc = 0.f;
  for (int u = 0; u < s; ++u)          // wave-uniform bound, no divergence
    cc = Als[u][dl] * cc + Bls[u][dl];

  const int poff = physk(d);                                   // fp8 byte offset
  const int bx2  = (((d & ~127) + physwb(d & 127)) >> 1);      // fp4 pair-byte offset
  for (int t0 = s * 64; t0 < s * 64 + 64; t0 += 8) {
    float pz[8], pf[8], po[8];
#pragma unroll
    for (int i = 0; i < 8; ++i) {
      const ushort* q = p + (size_t)(t0 + i) * G3;
      pz[i] = bf2f(q[0]); pf[i] = bf2f(q[512]); po[i] = bf2f(q[1024]);
    }
#pragma unroll
    for (int i = 0; i < 8; ++i) {
      float z = 2.f / (1.f + __expf(-2.f * pz[i])) - 1.f;
      float f = 1.f / (1.f + __expf(-pf[i]));
      float o = 1.f / (1.f + __expf(-po[i]));
      cc = f * cc + (1.f - f) * z;
      float h = o * cc;
      int tt = t0 + i;
      size_t r = (size_t)b * TT + tt;
      unsigned char nib = f2e2m1(h * 4.f);
      unsigned int pn = __shfl_xor((unsigned int)nib, 1, 64);  // partner (d^1) nibble
      if (mode == 0) {
        if ((dl & 1) == 0) {
          unsigned char byte = nib | ((unsigned char)pn << 4);
          OUT4[r * 512 + 256 + bx2] = byte;                    // x part
          if (tt < TT - 1) OUT4[(r + 1) * 512 + bx2] = byte;   // x_prev of next row
          if (tt == 0)     OUT4[r * 512 + bx2] = 0;
        }
      } else {
        OUT8[r * 512 + poff] = f2e4m3(h);
      }
    }
  }
}

// ---------------- final cost ----------------
__global__ __launch_bounds__(256) void cost_kernel(const float* __restrict__ sumexp,
                                                   const float* __restrict__ tgl,
                                                   float* __restrict__ out) {
  int t = threadIdx.x;
  float s = 0.f;
  for (int r = t; r < R; r += 256) s += logf(sumexp[r]) - tgl[r];
#pragma unroll
  for (int m = 1; m < 64; m <<= 1) s += __shfl_xor(s, m, 64);
  __shared__ float red[4];
  int wave = t >> 6, lane = t & 63;
  if (lane == 0) red[wave] = s;
  __syncthreads();
  if (t == 0) out[0] = (red[0] + red[1] + red[2] + red[3]) / (float)R;
}

extern "C" void kernel_launch(void* const* d_in, const int* in_sizes, int n_in,
                              void* d_out, int out_size, void* d_ws, size_t ws_size,
                              hipStream_t stream) {
  const int*   tok = (const int*)d_in[0];
  const int*   tgt = (const int*)d_in[1];
  const float* emb = (const float*)d_in[2];
  const float* Wz0 = (const float*)d_in[3];  const float* bz0 = (const float*)d_in[4];
  const float* Wf0 = (const float*)d_in[5];  const float* bf0 = (const float*)d_in[6];
  const float* Wo0 = (const float*)d_in[7];  const float* bo0 = (const float*)d_in[8];
  const float* Wz1 = (const float*)d_in[9];  const float* bz1 = (const float*)d_in[10];
  const float* Wf1 = (const float*)d_in[11]; const float* bf1 = (const float*)d_in[12];
  const float* Wo1 = (const float*)d_in[13]; const float* bo1 = (const float*)d_in[14];
  const float* SW  = (const float*)d_in[15]; const float* SB  = (const float*)d_in[16];
  float* out = (float*)d_out;

  // workspace layout (bytes), max ~49.7 MB:
  char* base = (char*)d_ws;
  unsigned char* XA4  = (unsigned char*)(base);             //  4,194,304 [R][512B] fp4
  unsigned char* YA4  = (unsigned char*)(base + 4194304);   //  4,194,304
  ushort*        PRE  = (ushort*)(base + 8388608);          // 25,165,824 [R][1536] bf16
  unsigned char* H8   = (unsigned char*)(base + 33554432);  //  4,194,304 [R][512B] fp8
  unsigned char* WT40 = (unsigned char*)(base + 37748736);  //    786,432 [1536][512B] fp4
  unsigned char* WT41 = (unsigned char*)(base + 38535168);  //    786,432
  float*         SUM  = (float*)(base + 39321600);          //     32,768
  float*         TGL  = (float*)(base + 39354368);          //     32,768
  unsigned char* H4   = (unsigned char*)(base + 39387136);  //  2,097,152 [R][256B] fp4
  unsigned char* SW4T = (unsigned char*)(base + 41484288);  //  8,192,000 [V][256B] fp4
  unsigned char* SW8T = (unsigned char*)(base);             // 16,384,000 — aliases XA4+YA4+PRE[0:8M] (dead by then)

  embed_kernel<<<R * 128 / 256, 256, 0, stream>>>(tok, (const float4*)emb, XA4);
  wconv<<<dim3(8, 8, 12), 256, 0, stream>>>(Wz0, Wf0, Wo0, Wz1, Wf1, Wo1, WT40, WT41);

  gemm_pre_fp4<123><<<dim3(32, 12), 256, 0, stream>>>(XA4, WT40, bz0, bf0, bo0, PRE);  // A=x*16
  scan_fused<<<dim3(32, 8), 256, 0, stream>>>(PRE, YA4, nullptr, 0);
  gemm_pre_fp4<125><<<dim3(32, 12), 256, 0, stream>>>(YA4, WT41, bz1, bf1, bo1, PRE);  // A=h*4
  scan_fused<<<dim3(32, 8), 256, 0, stream>>>(PRE, nullptr, H8, 1);

  // SW8T aliases XA4/YA4/PRE-head — all dead after the second scan
  swconv<<<dim3(8, 500), 256, 0, stream>>>(SW, SW8T, SW4T);
  h4pack<<<R * 512 / 8 / 256, 256, 0, stream>>>(H8, H4);
  tgl_kernel<<<R / 4, 256, 0, stream>>>(H8, SW8T, SB, tgt, TGL, SUM);
  gemm_lse_fp4<<<dim3(32, 250), 256, 0, stream>>>(H4, SW4T, SB, SUM);
  cost_kernel<<<1, 256, 0, stream>>>(SUM, TGL, out);
}

// Round 19
// 231.406 us; speedup vs baseline: 1.2645x; 1.1519x over previous
//
#include <hip/hip_runtime.h>
#include <hip/hip_bf16.h>
#include <math.h>

// Problem constants (B=32, T=256, V=32000, D=512)
#define R   8192    // B*T rows
#define TT  256
#define D   512
#define V   32000
#define G3  1536    // 3*D (z|f|o)

typedef __attribute__((ext_vector_type(4))) float f32x4;
typedef __attribute__((ext_vector_type(4))) int   i32x4;
typedef __attribute__((ext_vector_type(8))) int   i32x8;

__device__ __forceinline__ float bf2f(ushort u) {
  union { unsigned int i; float f; } x; x.i = ((unsigned int)u) << 16; return x.f;
}
__device__ __forceinline__ ushort f2bf(float f) {   // RNE
  union { float f; unsigned int i; } x; x.f = f;
  unsigned int r = x.i + 0x7fffu + ((x.i >> 16) & 1u);
  return (ushort)(r >> 16);
}

// raw hardware exp2: exactly the terminal op of __expf, no libm guards
__device__ __forceinline__ float hw_exp2(float x) {
  float r;
  asm("v_exp_f32 %0, %1" : "=v"(r) : "v"(x));
  return r;
}

// f32 (pre-scaled) -> fp4 e2m1 code, RNE to grid {0,.5,1,1.5,2,3,4,6}, clamp 6.
__device__ __forceinline__ unsigned char f2e2m1(float v) {
  unsigned char s = (v < 0.f) ? 8 : 0;
  float a = fabsf(v);
  unsigned char q;
  if      (a < 0.25f) q = 0;
  else if (a < 0.75f) q = 1;
  else if (a < 1.25f) q = 2;
  else if (a < 1.75f) q = 3;
  else if (a < 2.5f)  q = 4;
  else if (a < 3.5f)  q = 5;
  else if (a < 5.0f)  q = 6;
  else                q = 7;
  return s | q;
}

// e2m1 nibble -> f32 (arithmetic, no LUT: e=(n>>1)&3, m=n&1)
__device__ __forceinline__ float e2m1f(int n) {
  int e = (n >> 1) & 3, m = n & 1;
  float v;
  if (e == 0) v = 0.5f * (float)m;
  else { union { unsigned u; float f; } x;
         x.u = ((unsigned)(e + 126) << 23) | ((unsigned)m << 22); v = x.f; }
  return (n & 8) ? -v : v;
}

// within-128-block nibble offset of the phys-K map:
// elem k -> (k&~127) | h*32 | ks*8 | j,  k = (k&~127)+ks*32+h*8+j.
__device__ __forceinline__ int physwb(int k) {
  return (((k >> 3) & 3) << 5) | (((k >> 5) & 3) << 3) | (k & 7);
}
// full phys nibble offset for d within a row, then pair-byte offset (d even)
__device__ __forceinline__ int pairbyte(int d) {
  return (((d & ~127) + physwb(d & 127)) >> 1);
}

__device__ __forceinline__ void gload16(const void* g, void* l) {
  __builtin_amdgcn_global_load_lds((const __attribute__((address_space(1))) void*)g,
                                   (__attribute__((address_space(3))) void*)l, 16, 0, 0);
}

// ---------------- embedding gather -> XA4 fp4 phys-K [R][1024 elems]=[512B], x*16 ----------------
__global__ __launch_bounds__(256) void embed_kernel(const int* __restrict__ tok,
                                                    const float4* __restrict__ emb,
                                                    unsigned char* __restrict__ XA4) {
  int idx = blockIdx.x * 256 + threadIdx.x;   // over R*128 float4s
  int r = idx >> 7, d4 = idx & 127;
  float4 v = emb[(size_t)tok[r] * 128 + d4];
  int d = d4 * 4;
  unsigned char n0 = f2e2m1(v.x * 16.f), n1 = f2e2m1(v.y * 16.f);
  unsigned char n2 = f2e2m1(v.z * 16.f), n3 = f2e2m1(v.w * 16.f);
  uchar2 b2; b2.x = n0 | (n1 << 4); b2.y = n2 | (n3 << 4);
  int bx2 = pairbyte(d);
  *(uchar2*)(XA4 + (size_t)r * 512 + 256 + bx2) = b2;            // x part
  int t = r & (TT - 1);
  if (t < TT - 1) *(uchar2*)(XA4 + (size_t)(r + 1) * 512 + bx2) = b2;  // next row x_prev
  if (t == 0) { uchar2 z = {0, 0}; *(uchar2*)(XA4 + (size_t)r * 512 + bx2) = z; }
}

// ---------------- fp4 phys-K transpose-convert: 16 elems -> 8 bytes ----------------
__device__ __forceinline__ void tconv4_write(const float (*tile)[65],
                                             unsigned char* __restrict__ dstrow0,
                                             size_t ldb4, int k0, int t, float scale) {
  int nn = t & 63, h = t >> 6;
  union { unsigned char c[8]; uint2 q; } u;
#pragma unroll
  for (int ksl = 0; ksl < 2; ++ksl)
#pragma unroll
    for (int jp = 0; jp < 4; ++jp) {
      unsigned char l4 = f2e2m1(tile[ksl * 32 + h * 8 + jp * 2    ][nn] * scale);
      unsigned char h4 = f2e2m1(tile[ksl * 32 + h * 8 + jp * 2 + 1][nn] * scale);
      u.c[ksl * 4 + jp] = l4 | (h4 << 4);
    }
  unsigned char* dst = dstrow0 + (size_t)nn * ldb4 + ((k0 & ~127) >> 1) + h * 16 + ((k0 & 64) ? 8 : 0);
  *(uint2*)dst = u.q;
}

// ---------------- weight transpose+convert (BOTH layers): WT4[1536][512B] fp4 phys-K, W*16 ----------------
__global__ __launch_bounds__(256) void wconv(const float* __restrict__ Wz0,
                                             const float* __restrict__ Wf0,
                                             const float* __restrict__ Wo0,
                                             const float* __restrict__ Wz1,
                                             const float* __restrict__ Wf1,
                                             const float* __restrict__ Wo1,
                                             unsigned char* __restrict__ WT40,
                                             unsigned char* __restrict__ WT41) {
  __shared__ float tile[64][65];
  int z = blockIdx.z;
  int layer = z >= 6 ? 1 : 0, zz = z - 6 * layer;
  int g = zz >> 1, i = zz & 1;
  const float* src = layer == 0 ? (g == 0 ? Wz0 : (g == 1 ? Wf0 : Wo0))
                                : (g == 0 ? Wz1 : (g == 1 ? Wf1 : Wo1));
  unsigned char* WT4 = layer == 0 ? WT40 : WT41;
  src += (size_t)i * D * D;
  int d0 = blockIdx.x * 64, e0 = blockIdx.y * 64;
  int t = threadIdx.x, c = t & 63, rq = t >> 6;
#pragma unroll
  for (int p = 0; p < 16; ++p) {
    int dd = p * 4 + rq;
    tile[dd][c] = src[(size_t)(d0 + dd) * D + e0 + c];   // [k=d][n=e]
  }
  __syncthreads();
  tconv4_write(tile, WT4 + (size_t)(g * D + e0) * 512, 512, i * 512 + d0, t, 16.f);
}

// ---------------- softmax weight transpose+convert: fp4 x32 only ----------------
__global__ __launch_bounds__(256) void swconv(const float* __restrict__ SW,
                                              unsigned char* __restrict__ SW4T) {
  __shared__ float tile[64][65];
  int k0 = blockIdx.x * 64, n0 = blockIdx.y * 64;
  int t = threadIdx.x, c = t & 63, rq = t >> 6;
#pragma unroll
  for (int p = 0; p < 16; ++p) {
    int kk = p * 4 + rq;
    tile[kk][c] = SW[(size_t)(k0 + kk) * V + n0 + c];
  }
  __syncthreads();
  tconv4_write(tile, SW4T + (size_t)n0 * 256, 256, k0, t, 32.f);   // W x 2^5
}

// ---------------- shared MX-fp4 256x128 GEMM core (VERIFIED r16-r18) ----------------
// 256 thr / 4 waves; wave tile 128x64. Row-per-kt = 64B = 4 slots of 16B;
// phys slot = (logical + swz(r)) & 3, swz(r) = ((r&3)+((r>>2)&3))&3 (<=2-way, free).
// Swapped MFMA (mfma(W, A)): C row = lane&15 (lane-local), C col = (lane>>4)*4+j.
template<int LD4, int NKT, int WSC, int ASC>
__device__ __forceinline__ void mx4_core(const unsigned char* __restrict__ A4,
                                         const unsigned char* __restrict__ B4,
                                         int row0, int col0, char* lds,
                                         f32x4 acc[8][4]) {
  char* As = lds;            // 256 rows x 64B
  char* Bs = lds + 16384;    // 128 rows x 64B
  const int t = threadIdx.x, lane = t & 63, w = t >> 6;
  const int wm = w >> 1, wn = w & 1;
  const int lo = lane & 15, hi = lane >> 4;
  const int gr = t >> 2;                                       // row within issue
  const int ls = ((t & 3) - ((gr & 3) + ((gr >> 2) & 3))) & 3; // inverse-swz source slot

#pragma unroll 1
  for (int kt = 0; kt < NKT; ++kt) {
    const int k0b = kt * 64;                 // byte offset within row
#pragma unroll
    for (int i = 0; i < 4; ++i)
      gload16(A4 + (size_t)(row0 + i * 64 + gr) * LD4 + k0b + ls * 16,
              As + i * 4096 + t * 16);
#pragma unroll
    for (int i = 0; i < 2; ++i)
      gload16(B4 + (size_t)(col0 + i * 64 + gr) * LD4 + k0b + ls * 16,
              Bs + i * 4096 + t * 16);
    __syncthreads();
    i32x8 b4[4];
#pragma unroll
    for (int ni = 0; ni < 4; ++ni) {
      int r = wn * 64 + ni * 16 + lo;
      int ps = (hi + (r & 3) + ((r >> 2) & 3)) & 3;
      union { i32x8 v8; i32x4 v4[2]; } u;
      u.v4[0] = *(const i32x4*)(Bs + r * 64 + ps * 16);
      i32x4 z4 = {0, 0, 0, 0};
      u.v4[1] = z4;
      b4[ni] = u.v8;
    }
#pragma unroll
    for (int mi = 0; mi < 8; ++mi) {
      int r = wm * 128 + mi * 16 + lo;
      int ps = (hi + (r & 3) + ((r >> 2) & 3)) & 3;
      union { i32x8 v8; i32x4 v4[2]; } u;
      u.v4[0] = *(const i32x4*)(As + r * 64 + ps * 16);
      i32x4 z4 = {0, 0, 0, 0};
      u.v4[1] = z4;
      i32x8 a4 = u.v8;
#pragma unroll
      for (int ni = 0; ni < 4; ++ni)
        acc[mi][ni] = __builtin_amdgcn_mfma_scale_f32_16x16x128_f8f6f4(
            b4[ni], a4, acc[mi][ni], 4, 4, 0, WSC, 0, ASC);
    }
    __syncthreads();
  }
}

// ---------------- QRNN pre-activation GEMM (8192x1536x1024, MX-fp4, fused bias) ----------------
// ASC: layer1 A=x*16 -> 123; layer2 A=h*4 -> 125. W*16 -> 123.
template<int ASC>
__global__ __launch_bounds__(256, 2) void gemm_pre_fp4(const unsigned char* __restrict__ A4,
                                                       const unsigned char* __restrict__ B4,
                                                       const float* __restrict__ bz,
                                                       const float* __restrict__ bf,
                                                       const float* __restrict__ bo,
                                                       ushort* __restrict__ PRE) {
  __shared__ char lds[24576];
  const int t = threadIdx.x, lane = t & 63, w = t >> 6;
  const int wm = w >> 1, wn = w & 1;
  const int lo = lane & 15, hi = lane >> 4;
  const int row0 = blockIdx.x * 256, col0 = blockIdx.y * 128;
  const int g = col0 >> 9;                       // gate uniform per block
  const float* bg = (g == 0) ? bz : (g == 1 ? bf : bo);

  f32x4 acc[8][4];
#pragma unroll
  for (int i = 0; i < 8; ++i)
#pragma unroll
    for (int j = 0; j < 4; ++j) { f32x4 z = {0.f,0.f,0.f,0.f}; acc[i][j] = z; }

  mx4_core<512, 8, 123, ASC>(A4, B4, row0, col0, lds, acc);

#pragma unroll
  for (int mi = 0; mi < 8; ++mi) {
    const int row = row0 + wm * 128 + mi * 16 + lo;
#pragma unroll
    for (int ni = 0; ni < 4; ++ni) {
      const int colb = col0 + wn * 64 + ni * 16 + hi * 4;
      const int eb = colb & 511;
      ushort4 v;
      v.x = f2bf(acc[mi][ni][0] + bg[eb + 0]);
      v.y = f2bf(acc[mi][ni][1] + bg[eb + 1]);
      v.z = f2bf(acc[mi][ni][2] + bg[eb + 2]);
      v.w = f2bf(acc[mi][ni][3] + bg[eb + 3]);
      *(ushort4*)(PRE + (size_t)row * G3 + colb) = v;
    }
  }
}

// ---------------- target-logit kernel (+ SUM zero): fp4 path ----------------
// TGL[row] = dot(H4[row], SW4T[tgt]) / 128 + SB[tgt]  (H x4, W x32 scales)
__global__ __launch_bounds__(256) void tgl_kernel(const unsigned char* __restrict__ H4,
                                                  const unsigned char* __restrict__ SW4T,
                                                  const float* __restrict__ SB,
                                                  const int* __restrict__ tgt,
                                                  float* __restrict__ TGL,
                                                  float* __restrict__ SUM) {
  int wid  = (blockIdx.x * 256 + threadIdx.x) >> 6;   // one wave per row
  int lane = threadIdx.x & 63;
  if (lane == 0) SUM[wid] = 0.f;                      // zero before lse's atomics
  int tg = tgt[wid];
  unsigned int hv = *(const unsigned int*)(H4   + (size_t)wid * 256 + lane * 4);
  unsigned int wv = *(const unsigned int*)(SW4T + (size_t)tg  * 256 + lane * 4);
  float s = 0.f;
#pragma unroll
  for (int k = 0; k < 8; ++k)
    s += e2m1f((hv >> (4 * k)) & 15) * e2m1f((wv >> (4 * k)) & 15);
#pragma unroll
  for (int m = 1; m < 64; m <<= 1) s += __shfl_xor(s, m, 64);
  if (lane == 0) TGL[wid] = s * (1.f / 128.f) + SB[tg];
}

// ---------------- MX-fp4 logits GEMM + fused exp-sum (hw_exp2 epilogue) — r18 exact ----------------
__global__ __launch_bounds__(256, 2) void gemm_lse_fp4(const unsigned char* __restrict__ A4,
                                                       const unsigned char* __restrict__ B4,
                                                       const float* __restrict__ SB,
                                                       float* __restrict__ SUM) {
  __shared__ char lds[24576];
  const int t = threadIdx.x, lane = t & 63, w = t >> 6;
  const int wm = w >> 1, wn = w & 1;
  const int lo = lane & 15, hi = lane >> 4;
  const int row0 = blockIdx.x * 256, col0 = blockIdx.y * 128;
  const float L2E = 1.442695041f;

  float sb[16];   // SB * log2(e), pre-folded for the raw v_exp_f32
#pragma unroll
  for (int ni = 0; ni < 4; ++ni)
#pragma unroll
    for (int j = 0; j < 4; ++j)
      sb[ni * 4 + j] = SB[col0 + wn * 64 + ni * 16 + hi * 4 + j] * L2E;

  f32x4 acc[8][4];
#pragma unroll
  for (int i = 0; i < 8; ++i)
#pragma unroll
    for (int j = 0; j < 4; ++j) { f32x4 z = {0.f,0.f,0.f,0.f}; acc[i][j] = z; }

  mx4_core<256, 4, 122, 125>(A4, B4, row0, col0, lds, acc);  // W x2^-5, H x2^-2

#pragma unroll
  for (int mi = 0; mi < 8; ++mi) {
    const int row = row0 + wm * 128 + mi * 16 + lo;
    float s0 = 0.f, s1 = 0.f, s2 = 0.f, s3 = 0.f;
#pragma unroll
    for (int ni = 0; ni < 4; ++ni) {
      s0 += hw_exp2(fmaf(acc[mi][ni][0], L2E, sb[ni * 4 + 0]));
      s1 += hw_exp2(fmaf(acc[mi][ni][1], L2E, sb[ni * 4 + 1]));
      s2 += hw_exp2(fmaf(acc[mi][ni][2], L2E, sb[ni * 4 + 2]));
      s3 += hw_exp2(fmaf(acc[mi][ni][3], L2E, sb[ni * 4 + 3]));
    }
    float s = (s0 + s1) + (s2 + s3);
    s += __shfl_xor(s, 16, 64);
    s += __shfl_xor(s, 32, 64);
    if (hi == 0) atomicAdd(&SUM[row], s);
  }
}

// ---------------- fused 8-segment parallel fo-pool scan (512 thr, 2 waves/SIMD) ----------------
// Block = (64 d-values) x (8 segments of 32 steps); grid = (b 32, d-chunk 8).
// Phase 1: per-segment (A,B) over 32 steps. LDS exchange; compose c_init
// (<=7 fma, s wave-uniform). Phase 2: re-scan segment writing h as fp4 phys-K.
// mode 0: OUT4 = YA4 [R][512B] (x at 256+bx2, x_prev of next row at bx2, h*4).
// mode 1: OUT4 = H4 [R][256B] (at bx2).
__global__ __launch_bounds__(512) void scan_fused(const ushort* __restrict__ PRE,
                                                  unsigned char* __restrict__ OUT4,
                                                  int mode) {
  __shared__ float Als[8][64], Bls[8][64];
  const int b = blockIdx.x, dc = blockIdx.y;
  const int tid = threadIdx.x, dl = tid & 63, s = tid >> 6;   // s in 0..7, wave-uniform
  const int d = dc * 64 + dl;
  const ushort* p  = PRE + (size_t)b * TT * G3 + d;
  const ushort* ps = p + (size_t)(s * 32) * G3;

  float a = 1.f, c = 0.f;
  for (int t0 = 0; t0 < 32; t0 += 8) {
    float pz[8], pf[8];
#pragma unroll
    for (int i = 0; i < 8; ++i) {
      const ushort* q = ps + (size_t)(t0 + i) * G3;
      pz[i] = bf2f(q[0]); pf[i] = bf2f(q[512]);
    }
#pragma unroll
    for (int i = 0; i < 8; ++i) {
      float z = 2.f / (1.f + __expf(-2.f * pz[i])) - 1.f;
      float f = 1.f / (1.f + __expf(-pf[i]));
      c = f * c + (1.f - f) * z;
      a *= f;
    }
  }
  Als[s][dl] = a; Bls[s][dl] = c;
  __syncthreads();
  float cc = 0.f;
  for (int u = 0; u < s; ++u)          // wave-uniform bound, no divergence
    cc = Als[u][dl] * cc + Bls[u][dl];

  const int bx2 = pairbyte(d);
  for (int t0 = s * 32; t0 < s * 32 + 32; t0 += 8) {
    float pz[8], pf[8], po[8];
#pragma unroll
    for (int i = 0; i < 8; ++i) {
      const ushort* q = p + (size_t)(t0 + i) * G3;
      pz[i] = bf2f(q[0]); pf[i] = bf2f(q[512]); po[i] = bf2f(q[1024]);
    }
#pragma unroll
    for (int i = 0; i < 8; ++i) {
      float z = 2.f / (1.f + __expf(-2.f * pz[i])) - 1.f;
      float f = 1.f / (1.f + __expf(-pf[i]));
      float o = 1.f / (1.f + __expf(-po[i]));
      cc = f * cc + (1.f - f) * z;
      float h = o * cc;
      int tt = t0 + i;
      size_t r = (size_t)b * TT + tt;
      unsigned char nib = f2e2m1(h * 4.f);
      unsigned int pn = __shfl_xor((unsigned int)nib, 1, 64);  // partner (d^1) nibble
      if ((dl & 1) == 0) {
        unsigned char byte = nib | ((unsigned char)pn << 4);
        if (mode == 0) {
          OUT4[r * 512 + 256 + bx2] = byte;                    // x part
          if (tt < TT - 1) OUT4[(r + 1) * 512 + bx2] = byte;   // x_prev of next row
          if (tt == 0)     OUT4[r * 512 + bx2] = 0;
        } else {
          OUT4[r * 256 + bx2] = byte;
        }
      }
    }
  }
}

// ---------------- final cost ----------------
__global__ __launch_bounds__(256) void cost_kernel(const float* __restrict__ sumexp,
                                                   const float* __restrict__ tgl,
                                                   float* __restrict__ out) {
  int t = threadIdx.x;
  float s = 0.f;
  for (int r = t; r < R; r += 256) s += logf(sumexp[r]) - tgl[r];
#pragma unroll
  for (int m = 1; m < 64; m <<= 1) s += __shfl_xor(s, m, 64);
  __shared__ float red[4];
  int wave = t >> 6, lane = t & 63;
  if (lane == 0) red[wave] = s;
  __syncthreads();
  if (t == 0) out[0] = (red[0] + red[1] + red[2] + red[3]) / (float)R;
}

extern "C" void kernel_launch(void* const* d_in, const int* in_sizes, int n_in,
                              void* d_out, int out_size, void* d_ws, size_t ws_size,
                              hipStream_t stream) {
  const int*   tok = (const int*)d_in[0];
  const int*   tgt = (const int*)d_in[1];
  const float* emb = (const float*)d_in[2];
  const float* Wz0 = (const float*)d_in[3];  const float* bz0 = (const float*)d_in[4];
  const float* Wf0 = (const float*)d_in[5];  const float* bf0 = (const float*)d_in[6];
  const float* Wo0 = (const float*)d_in[7];  const float* bo0 = (const float*)d_in[8];
  const float* Wz1 = (const float*)d_in[9];  const float* bz1 = (const float*)d_in[10];
  const float* Wf1 = (const float*)d_in[11]; const float* bf1 = (const float*)d_in[12];
  const float* Wo1 = (const float*)d_in[13]; const float* bo1 = (const float*)d_in[14];
  const float* SW  = (const float*)d_in[15]; const float* SB  = (const float*)d_in[16];
  float* out = (float*)d_out;

  // workspace layout (bytes), max ~49.7 MB:
  char* base = (char*)d_ws;
  unsigned char* XA4  = (unsigned char*)(base);             //  4,194,304 [R][512B] fp4
  unsigned char* YA4  = (unsigned char*)(base + 4194304);   //  4,194,304
  ushort*        PRE  = (ushort*)(base + 8388608);          // 25,165,824 [R][1536] bf16
  unsigned char* WT40 = (unsigned char*)(base + 37748736);  //    786,432 [1536][512B] fp4
  unsigned char* WT41 = (unsigned char*)(base + 38535168);  //    786,432
  float*         SUM  = (float*)(base + 39321600);          //     32,768
  float*         TGL  = (float*)(base + 39354368);          //     32,768
  unsigned char* H4   = (unsigned char*)(base + 39387136);  //  2,097,152 [R][256B] fp4
  unsigned char* SW4T = (unsigned char*)(base + 41484288);  //  8,192,000 [V][256B] fp4

  embed_kernel<<<R * 128 / 256, 256, 0, stream>>>(tok, (const float4*)emb, XA4);
  wconv<<<dim3(8, 8, 12), 256, 0, stream>>>(Wz0, Wf0, Wo0, Wz1, Wf1, Wo1, WT40, WT41);

  gemm_pre_fp4<123><<<dim3(32, 12), 256, 0, stream>>>(XA4, WT40, bz0, bf0, bo0, PRE);  // A=x*16
  scan_fused<<<dim3(32, 8), 512, 0, stream>>>(PRE, YA4, 0);
  gemm_pre_fp4<125><<<dim3(32, 12), 256, 0, stream>>>(YA4, WT41, bz1, bf1, bo1, PRE);  // A=h*4
  scan_fused<<<dim3(32, 8), 512, 0, stream>>>(PRE, H4, 1);

  swconv<<<dim3(8, 500), 256, 0, stream>>>(SW, SW4T);
  tgl_kernel<<<R / 4, 256, 0, stream>>>(H4, SW4T, SB, tgt, TGL, SUM);
  gemm_lse_fp4<<<dim3(32, 250), 256, 0, stream>>>(H4, SW4T, SB, SUM);
  cost_kernel<<<1, 256, 0, stream>>>(SUM, TGL, out);
}

// Round 20
// 223.159 us; speedup vs baseline: 1.3112x; 1.0370x over previous
//
#include <hip/hip_runtime.h>
#include <hip/hip_bf16.h>
#include <math.h>

// Problem constants (B=32, T=256, V=32000, D=512)
#define R   8192    // B*T rows
#define TT  256
#define D   512
#define V   32000
#define G3  1536    // 3*D (z|f|o)

typedef __attribute__((ext_vector_type(4))) float f32x4;
typedef __attribute__((ext_vector_type(4))) int   i32x4;
typedef __attribute__((ext_vector_type(8))) int   i32x8;

__device__ __forceinline__ float bf2f(ushort u) {
  union { unsigned int i; float f; } x; x.i = ((unsigned int)u) << 16; return x.f;
}
__device__ __forceinline__ ushort f2bf(float f) {   // RNE
  union { float f; unsigned int i; } x; x.f = f;
  unsigned int r = x.i + 0x7fffu + ((x.i >> 16) & 1u);
  return (ushort)(r >> 16);
}

// raw hardware exp2: exactly the terminal op of __expf, no libm guards
__device__ __forceinline__ float hw_exp2(float x) {
  float r;
  asm("v_exp_f32 %0, %1" : "=v"(r) : "v"(x));
  return r;
}

// f32 (pre-scaled) -> fp4 e2m1 code, RNE to grid {0,.5,1,1.5,2,3,4,6}, clamp 6.
__device__ __forceinline__ unsigned char f2e2m1(float v) {
  unsigned char s = (v < 0.f) ? 8 : 0;
  float a = fabsf(v);
  unsigned char q;
  if      (a < 0.25f) q = 0;
  else if (a < 0.75f) q = 1;
  else if (a < 1.25f) q = 2;
  else if (a < 1.75f) q = 3;
  else if (a < 2.5f)  q = 4;
  else if (a < 3.5f)  q = 5;
  else if (a < 5.0f)  q = 6;
  else                q = 7;
  return s | q;
}

// e2m1 nibble -> f32 (arithmetic, no LUT)
__device__ __forceinline__ float e2m1f(int n) {
  int e = (n >> 1) & 3, m = n & 1;
  float v;
  if (e == 0) v = 0.5f * (float)m;
  else { union { unsigned u; float f; } x;
         x.u = ((unsigned)(e + 126) << 23) | ((unsigned)m << 22); v = x.f; }
  return (n & 8) ? -v : v;
}

// within-128-block nibble offset of the phys-K map
__device__ __forceinline__ int physwb(int k) {
  return (((k >> 3) & 3) << 5) | (((k >> 5) & 3) << 3) | (k & 7);
}
// pair-byte offset for even d
__device__ __forceinline__ int pairbyte(int d) {
  return (((d & ~127) + physwb(d & 127)) >> 1);
}

__device__ __forceinline__ void gload16(const void* g, void* l) {
  __builtin_amdgcn_global_load_lds((const __attribute__((address_space(1))) void*)g,
                                   (__attribute__((address_space(3))) void*)l, 16, 0, 0);
}

// ---------------- embedding gather -> XA4 fp4 phys-K [R][1024 elems]=[512B], x*16 ----------------
__global__ __launch_bounds__(256) void embed_kernel(const int* __restrict__ tok,
                                                    const float4* __restrict__ emb,
                                                    unsigned char* __restrict__ XA4) {
  int idx = blockIdx.x * 256 + threadIdx.x;   // over R*128 float4s
  int r = idx >> 7, d4 = idx & 127;
  float4 v = emb[(size_t)tok[r] * 128 + d4];
  int d = d4 * 4;
  unsigned char n0 = f2e2m1(v.x * 16.f), n1 = f2e2m1(v.y * 16.f);
  unsigned char n2 = f2e2m1(v.z * 16.f), n3 = f2e2m1(v.w * 16.f);
  uchar2 b2; b2.x = n0 | (n1 << 4); b2.y = n2 | (n3 << 4);
  int bx2 = pairbyte(d);
  *(uchar2*)(XA4 + (size_t)r * 512 + 256 + bx2) = b2;            // x part
  int t = r & (TT - 1);
  if (t < TT - 1) *(uchar2*)(XA4 + (size_t)(r + 1) * 512 + bx2) = b2;  // next row x_prev
  if (t == 0) { uchar2 z = {0, 0}; *(uchar2*)(XA4 + (size_t)r * 512 + bx2) = z; }
}

// ---------------- fp4 phys-K transpose-convert: 16 elems -> 8 bytes ----------------
__device__ __forceinline__ void tconv4_write(const float (*tile)[65],
                                             unsigned char* __restrict__ dstrow0,
                                             size_t ldb4, int k0, int t, float scale) {
  int nn = t & 63, h = t >> 6;
  union { unsigned char c[8]; uint2 q; } u;
#pragma unroll
  for (int ksl = 0; ksl < 2; ++ksl)
#pragma unroll
    for (int jp = 0; jp < 4; ++jp) {
      unsigned char l4 = f2e2m1(tile[ksl * 32 + h * 8 + jp * 2    ][nn] * scale);
      unsigned char h4 = f2e2m1(tile[ksl * 32 + h * 8 + jp * 2 + 1][nn] * scale);
      u.c[ksl * 4 + jp] = l4 | (h4 << 4);
    }
  unsigned char* dst = dstrow0 + (size_t)nn * ldb4 + ((k0 & ~127) >> 1) + h * 16 + ((k0 & 64) ? 8 : 0);
  *(uint2*)dst = u.q;
}

// ---------------- weight transpose+convert (BOTH layers): WT4[1536][512B] fp4 phys-K, W*16 ----------------
__global__ __launch_bounds__(256) void wconv(const float* __restrict__ Wz0,
                                             const float* __restrict__ Wf0,
                                             const float* __restrict__ Wo0,
                                             const float* __restrict__ Wz1,
                                             const float* __restrict__ Wf1,
                                             const float* __restrict__ Wo1,
                                             unsigned char* __restrict__ WT40,
                                             unsigned char* __restrict__ WT41) {
  __shared__ float tile[64][65];
  int z = blockIdx.z;
  int layer = z >= 6 ? 1 : 0, zz = z - 6 * layer;
  int g = zz >> 1, i = zz & 1;
  const float* src = layer == 0 ? (g == 0 ? Wz0 : (g == 1 ? Wf0 : Wo0))
                                : (g == 0 ? Wz1 : (g == 1 ? Wf1 : Wo1));
  unsigned char* WT4 = layer == 0 ? WT40 : WT41;
  src += (size_t)i * D * D;
  int d0 = blockIdx.x * 64, e0 = blockIdx.y * 64;
  int t = threadIdx.x, c = t & 63, rq = t >> 6;
#pragma unroll
  for (int p = 0; p < 16; ++p) {
    int dd = p * 4 + rq;
    tile[dd][c] = src[(size_t)(d0 + dd) * D + e0 + c];   // [k=d][n=e]
  }
  __syncthreads();
  tconv4_write(tile, WT4 + (size_t)(g * D + e0) * 512, 512, i * 512 + d0, t, 16.f);
}

// ---------------- softmax weight transpose+convert: fp4 x32 ----------------
__global__ __launch_bounds__(256) void swconv(const float* __restrict__ SW,
                                              unsigned char* __restrict__ SW4T) {
  __shared__ float tile[64][65];
  int k0 = blockIdx.x * 64, n0 = blockIdx.y * 64;
  int t = threadIdx.x, c = t & 63, rq = t >> 6;
#pragma unroll
  for (int p = 0; p < 16; ++p) {
    int kk = p * 4 + rq;
    tile[kk][c] = SW[(size_t)(k0 + kk) * V + n0 + c];
  }
  __syncthreads();
  tconv4_write(tile, SW4T + (size_t)n0 * 256, 256, k0, t, 32.f);   // W x 2^5
}

// ---------------- MX-fp4 128x128 GEMM core (r9 structure at fp4; for gemm_pre) ----------------
// 256 thr / 4 waves (2x2 of 64x64 wave tiles). Row-per-kt = 64B = 4 slots of 16B;
// phys slot = (logical + swz(r)) & 3, swz(r) = ((r&3)+((r>>2)&3))&3 (<=2-way, free).
// Swapped MFMA (mfma(W, A)): C row = lane&15 (lane-local), C col = (lane>>4)*4+j.
// LDS = A 8KB + B 8KB = 16KB -> more resident blocks; grid 768 = 3 blocks/CU.
template<int LD4, int NKT, int WSC, int ASC>
__device__ __forceinline__ void mx4_core128(const unsigned char* __restrict__ A4,
                                            const unsigned char* __restrict__ B4,
                                            int row0, int col0, char* lds,
                                            f32x4 acc[4][4]) {
  char* As = lds;            // 128 rows x 64B
  char* Bs = lds + 8192;     // 128 rows x 64B
  const int t = threadIdx.x, lane = t & 63, w = t >> 6;
  const int wm = w >> 1, wn = w & 1;
  const int lo = lane & 15, hi = lane >> 4;
  const int gr = t >> 2;                                       // row within 64-row issue
  const int ls = ((t & 3) - ((gr & 3) + ((gr >> 2) & 3))) & 3; // inverse-swz source slot

#pragma unroll 1
  for (int kt = 0; kt < NKT; ++kt) {
    const int k0b = kt * 64;
#pragma unroll
    for (int i = 0; i < 2; ++i) {
      gload16(A4 + (size_t)(row0 + i * 64 + gr) * LD4 + k0b + ls * 16,
              As + i * 4096 + t * 16);
      gload16(B4 + (size_t)(col0 + i * 64 + gr) * LD4 + k0b + ls * 16,
              Bs + i * 4096 + t * 16);
    }
    __syncthreads();
    i32x8 b4[4];
#pragma unroll
    for (int ni = 0; ni < 4; ++ni) {
      int r = wn * 64 + ni * 16 + lo;
      int ps = (hi + (r & 3) + ((r >> 2) & 3)) & 3;
      union { i32x8 v8; i32x4 v4[2]; } u;
      u.v4[0] = *(const i32x4*)(Bs + r * 64 + ps * 16);
      i32x4 z4 = {0, 0, 0, 0};
      u.v4[1] = z4;
      b4[ni] = u.v8;
    }
#pragma unroll
    for (int mi = 0; mi < 4; ++mi) {
      int r = wm * 64 + mi * 16 + lo;
      int ps = (hi + (r & 3) + ((r >> 2) & 3)) & 3;
      union { i32x8 v8; i32x4 v4[2]; } u;
      u.v4[0] = *(const i32x4*)(As + r * 64 + ps * 16);
      i32x4 z4 = {0, 0, 0, 0};
      u.v4[1] = z4;
      i32x8 a4 = u.v8;
#pragma unroll
      for (int ni = 0; ni < 4; ++ni)
        acc[mi][ni] = __builtin_amdgcn_mfma_scale_f32_16x16x128_f8f6f4(
            b4[ni], a4, acc[mi][ni], 4, 4, 0, WSC, 0, ASC);
    }
    __syncthreads();
  }
}

// ---------------- QRNN pre-activation GEMM (8192x1536x1024, MX-fp4, 128x128, fused bias) ----------------
// ASC: layer1 A=x*16 -> 123; layer2 A=h*4 -> 125. W*16 -> 123.
template<int ASC>
__global__ __launch_bounds__(256, 2) void gemm_pre_fp4(const unsigned char* __restrict__ A4,
                                                       const unsigned char* __restrict__ B4,
                                                       const float* __restrict__ bz,
                                                       const float* __restrict__ bf,
                                                       const float* __restrict__ bo,
                                                       ushort* __restrict__ PRE) {
  __shared__ char lds[16384];
  const int t = threadIdx.x, lane = t & 63, w = t >> 6;
  const int wm = w >> 1, wn = w & 1;
  const int lo = lane & 15, hi = lane >> 4;
  const int row0 = blockIdx.x * 128, col0 = blockIdx.y * 128;
  const int g = col0 >> 9;                       // gate uniform per block
  const float* bg = (g == 0) ? bz : (g == 1 ? bf : bo);

  f32x4 acc[4][4];
#pragma unroll
  for (int i = 0; i < 4; ++i)
#pragma unroll
    for (int j = 0; j < 4; ++j) { f32x4 z = {0.f,0.f,0.f,0.f}; acc[i][j] = z; }

  mx4_core128<512, 8, 123, ASC>(A4, B4, row0, col0, lds, acc);

#pragma unroll
  for (int mi = 0; mi < 4; ++mi) {
    const int row = row0 + wm * 64 + mi * 16 + lo;
#pragma unroll
    for (int ni = 0; ni < 4; ++ni) {
      const int colb = col0 + wn * 64 + ni * 16 + hi * 4;
      const int eb = colb & 511;
      ushort4 v;
      v.x = f2bf(acc[mi][ni][0] + bg[eb + 0]);
      v.y = f2bf(acc[mi][ni][1] + bg[eb + 1]);
      v.z = f2bf(acc[mi][ni][2] + bg[eb + 2]);
      v.w = f2bf(acc[mi][ni][3] + bg[eb + 3]);
      *(ushort4*)(PRE + (size_t)row * G3 + colb) = v;
    }
  }
}

// ---------------- target-logit kernel (+ SUM zero): fp4 path ----------------
__global__ __launch_bounds__(256) void tgl_kernel(const unsigned char* __restrict__ H4,
                                                  const unsigned char* __restrict__ SW4T,
                                                  const float* __restrict__ SB,
                                                  const int* __restrict__ tgt,
                                                  float* __restrict__ TGL,
                                                  float* __restrict__ SUM) {
  int wid  = (blockIdx.x * 256 + threadIdx.x) >> 6;   // one wave per row
  int lane = threadIdx.x & 63;
  if (lane == 0) SUM[wid] = 0.f;                      // zero before lse's atomics
  int tg = tgt[wid];
  unsigned int hv = *(const unsigned int*)(H4   + (size_t)wid * 256 + lane * 4);
  unsigned int wv = *(const unsigned int*)(SW4T + (size_t)tg  * 256 + lane * 4);
  float s = 0.f;
#pragma unroll
  for (int k = 0; k < 8; ++k)
    s += e2m1f((hv >> (4 * k)) & 15) * e2m1f((wv >> (4 * k)) & 15);
#pragma unroll
  for (int m = 1; m < 64; m <<= 1) s += __shfl_xor(s, m, 64);
  if (lane == 0) TGL[wid] = s * (1.f / 128.f) + SB[tg];
}

// ---------------- shared MX-fp4 256x128 GEMM core (VERIFIED r16-r19; for lse) ----------------
template<int LD4, int NKT, int WSC, int ASC>
__device__ __forceinline__ void mx4_core(const unsigned char* __restrict__ A4,
                                         const unsigned char* __restrict__ B4,
                                         int row0, int col0, char* lds,
                                         f32x4 acc[8][4]) {
  char* As = lds;            // 256 rows x 64B
  char* Bs = lds + 16384;    // 128 rows x 64B
  const int t = threadIdx.x, lane = t & 63, w = t >> 6;
  const int wm = w >> 1, wn = w & 1;
  const int lo = lane & 15, hi = lane >> 4;
  const int gr = t >> 2;                                       // row within issue
  const int ls = ((t & 3) - ((gr & 3) + ((gr >> 2) & 3))) & 3; // inverse-swz source slot

#pragma unroll 1
  for (int kt = 0; kt < NKT; ++kt) {
    const int k0b = kt * 64;
#pragma unroll
    for (int i = 0; i < 4; ++i)
      gload16(A4 + (size_t)(row0 + i * 64 + gr) * LD4 + k0b + ls * 16,
              As + i * 4096 + t * 16);
#pragma unroll
    for (int i = 0; i < 2; ++i)
      gload16(B4 + (size_t)(col0 + i * 64 + gr) * LD4 + k0b + ls * 16,
              Bs + i * 4096 + t * 16);
    __syncthreads();
    i32x8 b4[4];
#pragma unroll
    for (int ni = 0; ni < 4; ++ni) {
      int r = wn * 64 + ni * 16 + lo;
      int ps = (hi + (r & 3) + ((r >> 2) & 3)) & 3;
      union { i32x8 v8; i32x4 v4[2]; } u;
      u.v4[0] = *(const i32x4*)(Bs + r * 64 + ps * 16);
      i32x4 z4 = {0, 0, 0, 0};
      u.v4[1] = z4;
      b4[ni] = u.v8;
    }
#pragma unroll
    for (int mi = 0; mi < 8; ++mi) {
      int r = wm * 128 + mi * 16 + lo;
      int ps = (hi + (r & 3) + ((r >> 2) & 3)) & 3;
      union { i32x8 v8; i32x4 v4[2]; } u;
      u.v4[0] = *(const i32x4*)(As + r * 64 + ps * 16);
      i32x4 z4 = {0, 0, 0, 0};
      u.v4[1] = z4;
      i32x8 a4 = u.v8;
#pragma unroll
      for (int ni = 0; ni < 4; ++ni)
        acc[mi][ni] = __builtin_amdgcn_mfma_scale_f32_16x16x128_f8f6f4(
            b4[ni], a4, acc[mi][ni], 4, 4, 0, WSC, 0, ASC);
    }
    __syncthreads();
  }
}

// ---------------- MX-fp4 logits GEMM + fused exp-sum (hw_exp2 epilogue) — r18/r19 exact ----------------
__global__ __launch_bounds__(256, 2) void gemm_lse_fp4(const unsigned char* __restrict__ A4,
                                                       const unsigned char* __restrict__ B4,
                                                       const float* __restrict__ SB,
                                                       float* __restrict__ SUM) {
  __shared__ char lds[24576];
  const int t = threadIdx.x, lane = t & 63, w = t >> 6;
  const int wm = w >> 1, wn = w & 1;
  const int lo = lane & 15, hi = lane >> 4;
  const int row0 = blockIdx.x * 256, col0 = blockIdx.y * 128;
  const float L2E = 1.442695041f;

  float sb[16];   // SB * log2(e), pre-folded for the raw v_exp_f32
#pragma unroll
  for (int ni = 0; ni < 4; ++ni)
#pragma unroll
    for (int j = 0; j < 4; ++j)
      sb[ni * 4 + j] = SB[col0 + wn * 64 + ni * 16 + hi * 4 + j] * L2E;

  f32x4 acc[8][4];
#pragma unroll
  for (int i = 0; i < 8; ++i)
#pragma unroll
    for (int j = 0; j < 4; ++j) { f32x4 z = {0.f,0.f,0.f,0.f}; acc[i][j] = z; }

  mx4_core<256, 4, 122, 125>(A4, B4, row0, col0, lds, acc);  // W x2^-5, H x2^-2

#pragma unroll
  for (int mi = 0; mi < 8; ++mi) {
    const int row = row0 + wm * 128 + mi * 16 + lo;
    float s0 = 0.f, s1 = 0.f, s2 = 0.f, s3 = 0.f;
#pragma unroll
    for (int ni = 0; ni < 4; ++ni) {
      s0 += hw_exp2(fmaf(acc[mi][ni][0], L2E, sb[ni * 4 + 0]));
      s1 += hw_exp2(fmaf(acc[mi][ni][1], L2E, sb[ni * 4 + 1]));
      s2 += hw_exp2(fmaf(acc[mi][ni][2], L2E, sb[ni * 4 + 2]));
      s3 += hw_exp2(fmaf(acc[mi][ni][3], L2E, sb[ni * 4 + 3]));
    }
    float s = (s0 + s1) + (s2 + s3);
    s += __shfl_xor(s, 16, 64);
    s += __shfl_xor(s, 32, 64);
    if (hi == 0) atomicAdd(&SUM[row], s);
  }
}

// ---------------- fused 8-segment parallel fo-pool scan (512 thr; z,f reg-cached) ----------------
// Phase 1 loads its segment's (z,f) ONCE into 64 statically-indexed VGPRs and
// computes (A,B); phase 2 reuses them and reads only o (-2/3 PRE re-read).
__global__ __launch_bounds__(512) void scan_fused(const ushort* __restrict__ PRE,
                                                  unsigned char* __restrict__ OUT4,
                                                  int mode) {
  __shared__ float Als[8][64], Bls[8][64];
  const int b = blockIdx.x, dc = blockIdx.y;
  const int tid = threadIdx.x, dl = tid & 63, s = tid >> 6;   // s in 0..7, wave-uniform
  const int d = dc * 64 + dl;
  const ushort* p  = PRE + (size_t)b * TT * G3 + d;
  const ushort* ps = p + (size_t)(s * 32) * G3;

  float zs[32], fs[32];
  float a = 1.f, c = 0.f;
#pragma unroll
  for (int t0 = 0; t0 < 32; t0 += 8) {
    float pz[8], pf[8];
#pragma unroll
    for (int i = 0; i < 8; ++i) {
      const ushort* q = ps + (size_t)(t0 + i) * G3;
      pz[i] = bf2f(q[0]); pf[i] = bf2f(q[512]);
    }
#pragma unroll
    for (int i = 0; i < 8; ++i) {
      float z = 2.f / (1.f + __expf(-2.f * pz[i])) - 1.f;
      float f = 1.f / (1.f + __expf(-pf[i]));
      zs[t0 + i] = z; fs[t0 + i] = f;
      c = f * c + (1.f - f) * z;
      a *= f;
    }
  }
  Als[s][dl] = a; Bls[s][dl] = c;
  __syncthreads();
  float cc = 0.f;
  for (int u = 0; u < s; ++u)          // wave-uniform bound, no divergence
    cc = Als[u][dl] * cc + Bls[u][dl];

  const int bx2 = pairbyte(d);
#pragma unroll
  for (int t0 = 0; t0 < 32; t0 += 8) {
    float po[8];
#pragma unroll
    for (int i = 0; i < 8; ++i)
      po[i] = bf2f(ps[(size_t)(t0 + i) * G3 + 1024]);
#pragma unroll
    for (int i = 0; i < 8; ++i) {
      float o = 1.f / (1.f + __expf(-po[i]));
      float f = fs[t0 + i];
      cc = f * cc + (1.f - f) * zs[t0 + i];
      float h = o * cc;
      int tt = s * 32 + t0 + i;
      size_t r = (size_t)b * TT + tt;
      unsigned char nib = f2e2m1(h * 4.f);
      unsigned int pn = __shfl_xor((unsigned int)nib, 1, 64);  // partner (d^1) nibble
      if ((dl & 1) == 0) {
        unsigned char byte = nib | ((unsigned char)pn << 4);
        if (mode == 0) {
          OUT4[r * 512 + 256 + bx2] = byte;                    // x part
          if (tt < TT - 1) OUT4[(r + 1) * 512 + bx2] = byte;   // x_prev of next row
          if (tt == 0)     OUT4[r * 512 + bx2] = 0;
        } else {
          OUT4[r * 256 + bx2] = byte;
        }
      }
    }
  }
}

// ---------------- final cost ----------------
__global__ __launch_bounds__(256) void cost_kernel(const float* __restrict__ sumexp,
                                                   const float* __restrict__ tgl,
                                                   float* __restrict__ out) {
  int t = threadIdx.x;
  float s = 0.f;
  for (int r = t; r < R; r += 256) s += logf(sumexp[r]) - tgl[r];
#pragma unroll
  for (int m = 1; m < 64; m <<= 1) s += __shfl_xor(s, m, 64);
  __shared__ float red[4];
  int wave = t >> 6, lane = t & 63;
  if (lane == 0) red[wave] = s;
  __syncthreads();
  if (t == 0) out[0] = (red[0] + red[1] + red[2] + red[3]) / (float)R;
}

extern "C" void kernel_launch(void* const* d_in, const int* in_sizes, int n_in,
                              void* d_out, int out_size, void* d_ws, size_t ws_size,
                              hipStream_t stream) {
  const int*   tok = (const int*)d_in[0];
  const int*   tgt = (const int*)d_in[1];
  const float* emb = (const float*)d_in[2];
  const float* Wz0 = (const float*)d_in[3];  const float* bz0 = (const float*)d_in[4];
  const float* Wf0 = (const float*)d_in[5];  const float* bf0 = (const float*)d_in[6];
  const float* Wo0 = (const float*)d_in[7];  const float* bo0 = (const float*)d_in[8];
  const float* Wz1 = (const float*)d_in[9];  const float* bz1 = (const float*)d_in[10];
  const float* Wf1 = (const float*)d_in[11]; const float* bf1 = (const float*)d_in[12];
  const float* Wo1 = (const float*)d_in[13]; const float* bo1 = (const float*)d_in[14];
  const float* SW  = (const float*)d_in[15]; const float* SB  = (const float*)d_in[16];
  float* out = (float*)d_out;

  // workspace layout (bytes), max ~49.7 MB:
  char* base = (char*)d_ws;
  unsigned char* XA4  = (unsigned char*)(base);             //  4,194,304 [R][512B] fp4
  unsigned char* YA4  = (unsigned char*)(base + 4194304);   //  4,194,304
  ushort*        PRE  = (ushort*)(base + 8388608);          // 25,165,824 [R][1536] bf16
  unsigned char* WT40 = (unsigned char*)(base + 37748736);  //    786,432 [1536][512B] fp4
  unsigned char* WT41 = (unsigned char*)(base + 38535168);  //    786,432
  float*         SUM  = (float*)(base + 39321600);          //     32,768
  float*         TGL  = (float*)(base + 39354368);          //     32,768
  unsigned char* H4   = (unsigned char*)(base + 39387136);  //  2,097,152 [R][256B] fp4
  unsigned char* SW4T = (unsigned char*)(base + 41484288);  //  8,192,000 [V][256B] fp4

  embed_kernel<<<R * 128 / 256, 256, 0, stream>>>(tok, (const float4*)emb, XA4);
  wconv<<<dim3(8, 8, 12), 256, 0, stream>>>(Wz0, Wf0, Wo0, Wz1, Wf1, Wo1, WT40, WT41);

  gemm_pre_fp4<123><<<dim3(64, 12), 256, 0, stream>>>(XA4, WT40, bz0, bf0, bo0, PRE);  // A=x*16
  scan_fused<<<dim3(32, 8), 512, 0, stream>>>(PRE, YA4, 0);
  gemm_pre_fp4<125><<<dim3(64, 12), 256, 0, stream>>>(YA4, WT41, bz1, bf1, bo1, PRE);  // A=h*4
  scan_fused<<<dim3(32, 8), 512, 0, stream>>>(PRE, H4, 1);

  swconv<<<dim3(8, 500), 256, 0, stream>>>(SW, SW4T);
  tgl_kernel<<<R / 4, 256, 0, stream>>>(H4, SW4T, SB, tgt, TGL, SUM);
  gemm_lse_fp4<<<dim3(32, 250), 256, 0, stream>>>(H4, SW4T, SB, SUM);
  cost_kernel<<<1, 256, 0, stream>>>(SUM, TGL, out);
}